// Round 9
// baseline (456.488 us; speedup 1.0000x reference)
//
#include <hip/hip_runtime.h>

#define HW 65536

typedef __attribute__((ext_vector_type(8))) short short8;
typedef __attribute__((ext_vector_type(4))) float float4v;

__device__ __forceinline__ int refl(int i){ if (i < 0) i = -i; if (i > 255) i = 510 - i; return i; }
__device__ __forceinline__ float lrelu(float x){ return x > 0.f ? x : 0.01f * x; }
__device__ __forceinline__ unsigned short f2bf(float x){
  union { float f; unsigned int u; } v; v.f = x;
  unsigned int r = v.u + 0x7fff + ((v.u >> 16) & 1);
  return (unsigned short)(r >> 16);
}

// ---------------- K1: grid sample -> TRANSPOSED tilt (tiltT[c][x*256+y]) ----------------
// block = x column, thread = y: tiltT writes are contiguous per block.
__global__ __launch_bounds__(256) void k_gridsample2(const float* __restrict__ img,
                                                     const float* __restrict__ zern,
                                                     float* __restrict__ tiltT){
  int x = blockIdx.x, y = threadIdx.x;
  int pix = y * 256 + x;
  float px = zern[pix * 35 + 0], py = zern[pix * 35 + 1];
  float ix = ((float)x + px) * (256.f / 255.f) - 0.5f;
  float iy = ((float)y + py) * (256.f / 255.f) - 0.5f;
  ix = fminf(fmaxf(ix, 0.f), 255.f);
  iy = fminf(fmaxf(iy, 0.f), 255.f);
  float x0f = floorf(ix), y0f = floorf(iy);
  float wx = ix - x0f, wy = iy - y0f;
  int x0 = (int)x0f, y0 = (int)y0f;
  int x1 = min(x0 + 1, 255), y1 = min(y0 + 1, 255);
  #pragma unroll
  for (int c = 0; c < 3; ++c){
    const float* im = img + c * HW;
    float g00 = im[y0 * 256 + x0], g01 = im[y0 * 256 + x1];
    float g10 = im[y1 * 256 + x0], g11 = im[y1 * 256 + x1];
    float top = g00 * (1.f - wx) + g01 * wx;
    float bot = g10 * (1.f - wx) + g11 * wx;
    tiltT[c * HW + x * 256 + y] = top * (1.f - wy) + bot * wy;
  }
}

// ---------------- Weight convert: fp32 -> zero-padded bf16 ------------------------------
#define W2OFF 13312
#define W3OFF 59904
__global__ __launch_bounds__(256) void k_wcvt(const float* __restrict__ w1,
    const float* __restrict__ w2, const float* __restrict__ w3,
    unsigned short* __restrict__ wbf){
  int i = blockIdx.x * 256 + threadIdx.x;
  if (i < 208 * 64){
    int n = i >> 6, k = i & 63;
    float v = (n < 200 && k < 33) ? w1[n * 33 + k] : 0.f;
    wbf[i] = f2bf(v);
  } else if (i < W2OFF + 208 * 224){
    int j = i - W2OFF; int n = j / 224, k = j - n * 224;
    float v = (n < 200 && k < 200) ? w2[n * 200 + k] : 0.f;
    wbf[i] = f2bf(v);
  } else if (i < 84992){
    int j = i - W3OFF; int n = j / 224, k = j - n * 224;
    float v = (n < 100 && k < 200) ? w3[n * 200 + k] : 0.f;
    wbf[i] = f2bf(v);
  }
}

// ---------------- Fused MLP: 64-pixel COLUMN tile, writes TRANSPOSED coef ---------------
// block b: x = b>>2, y0 = (b&3)*64; pixels (y0+m, x). coefT[q][x*256+y] contiguous write.
#define HSTR 232
__global__ __launch_bounds__(256, 1) void k_mlp(const float* __restrict__ zern,
    const float* __restrict__ b1f, const float* __restrict__ b2f,
    const float* __restrict__ b3f, const unsigned short* __restrict__ wbf,
    float* __restrict__ coefT){
  __shared__ char smem[59392];
  unsigned short* H1 = (unsigned short*)smem;
  float*          H3 = (float*)smem;
  unsigned short* XB = (unsigned short*)(smem + 29696);
  unsigned short* H2 = XB;
  int tid = threadIdx.x;
  int xcol = blockIdx.x >> 2;
  int y0   = (blockIdx.x & 3) * 64;
  int lane = tid & 63, wv = tid >> 6;
  int ln = lane & 15, qd = lane >> 4;

  for (int e = tid; e < 2304; e += 256) ((int*)XB)[e] = 0;
  for (int e = tid; e < 768; e += 256){
    int m = e / 12, j = e - m * 12;
    ((int*)H1)[m * 116 + 104 + j] = 0;
  }
  __syncthreads();
  for (int e = tid; e < 64 * 33; e += 256){
    int m = e / 33, k = e - m * 33;
    XB[m * 72 + k] = f2bf(zern[((y0 + m) * 256 + xcol) * 35 + 2 + k]);
  }
  __syncthreads();

  // ---- layer 1 ----
  for (int nt = wv; nt < 13; nt += 4){
    int n = nt * 16 + ln;
    short8 b0 = *(const short8*)(wbf + n * 64 + qd * 8);
    short8 b1 = *(const short8*)(wbf + n * 64 + 32 + qd * 8);
    float bv = (n < 200) ? b1f[n] : 0.f;
    #pragma unroll
    for (int mt = 0; mt < 4; ++mt){
      float4v acc = {bv, bv, bv, bv};
      short8 a0 = *(const short8*)(XB + (mt * 16 + ln) * 72 + qd * 8);
      short8 a1 = *(const short8*)(XB + (mt * 16 + ln) * 72 + 32 + qd * 8);
      acc = __builtin_amdgcn_mfma_f32_16x16x32_bf16(a0, b0, acc, 0, 0, 0);
      acc = __builtin_amdgcn_mfma_f32_16x16x32_bf16(a1, b1, acc, 0, 0, 0);
      #pragma unroll
      for (int r = 0; r < 4; ++r)
        H1[(mt * 16 + qd * 4 + r) * HSTR + n] = f2bf(lrelu(acc[r]));
    }
  }
  __syncthreads();

  // ---- layer 2 ----
  for (int e = tid; e < 768; e += 256){
    int m = e / 12, j = e - m * 12;
    ((int*)H2)[m * 116 + 104 + j] = 0;
  }
  {
    const unsigned short* w2p = wbf + W2OFF;
    for (int nt = wv; nt < 13; nt += 4){
      int n = nt * 16 + ln;
      short8 bf[7];
      #pragma unroll
      for (int kc = 0; kc < 7; ++kc)
        bf[kc] = *(const short8*)(w2p + n * 224 + kc * 32 + qd * 8);
      float bv = (n < 200) ? b2f[n] : 0.f;
      #pragma unroll
      for (int mt = 0; mt < 4; ++mt){
        float4v acc = {bv, bv, bv, bv};
        #pragma unroll
        for (int kc = 0; kc < 7; ++kc){
          short8 af = *(const short8*)(H1 + (mt * 16 + ln) * HSTR + kc * 32 + qd * 8);
          acc = __builtin_amdgcn_mfma_f32_16x16x32_bf16(af, bf[kc], acc, 0, 0, 0);
        }
        #pragma unroll
        for (int r = 0; r < 4; ++r)
          H2[(mt * 16 + qd * 4 + r) * HSTR + n] = f2bf(lrelu(acc[r]));
      }
    }
  }
  __syncthreads();

  // ---- layer 3 ----
  {
    const unsigned short* w3p = wbf + W3OFF;
    for (int nt = wv; nt < 7; nt += 4){
      int n = nt * 16 + ln;
      short8 bf[7];
      #pragma unroll
      for (int kc = 0; kc < 7; ++kc)
        bf[kc] = *(const short8*)(w3p + n * 224 + kc * 32 + qd * 8);
      float bv = (n < 100) ? b3f[n] : 0.f;
      #pragma unroll
      for (int mt = 0; mt < 4; ++mt){
        float4v acc = {bv, bv, bv, bv};
        #pragma unroll
        for (int kc = 0; kc < 7; ++kc){
          short8 af = *(const short8*)(H2 + (mt * 16 + ln) * HSTR + kc * 32 + qd * 8);
          acc = __builtin_amdgcn_mfma_f32_16x16x32_bf16(af, bf[kc], acc, 0, 0, 0);
        }
        #pragma unroll
        for (int r = 0; r < 4; ++r)
          H3[(mt * 16 + qd * 4 + r) * 113 + n] = acc[r];
      }
    }
  }
  __syncthreads();

  for (int e = tid; e < 100 * 64; e += 256){
    int n = e >> 6, m = e & 63;
    coefT[n * HW + xcol * 256 + y0 + m] = H3[m * 113 + n];
  }
}

// ---------------- K3 v7: vertical conv on TRANSPOSED planes — no LDS, no barriers -------
// Thread owns column x, rows [yb, yb+16). Window = 80 CONTIGUOUS floats from coefT/tiltT.
// bid < 640: (c 0..3, j 0..9, s 0..15): S_{c,j} = sum_i vconv(X_{c,i10+j}, L_i) -> ST
// bid >= 640: (c 0..2, s): Smu_{c,m} = vconv(tiltT_c, mu_m), m 0..9 -> STmu
__global__ __launch_bounds__(256) void k_vconv7(const float* __restrict__ tiltT,
    const float* __restrict__ coefT, const float* __restrict__ bl,
    const float* __restrict__ mu, float* __restrict__ ST, float* __restrict__ STmu){
  int tid = threadIdx.x;
  int bid = blockIdx.x;
  int tx = tid & 15, yg = tid >> 4;
  int yb = yg * 16;

  if (bid < 640){
    int s = bid & 15;
    int cj = bid >> 4;
    int c = cj / 10, j = cj - c * 10;
    int x = s * 16 + tx;
    const float* tcol = tiltT + (c < 3 ? c : 0) * HW + x * 256;
    float acc[16];
    #pragma unroll
    for (int r = 0; r < 16; ++r) acc[r] = 0.f;
    for (int i = 0; i < 10; ++i){
      const float* cq = coefT + (i * 10 + j) * HW + x * 256;
      float w[80];
      #pragma unroll
      for (int k = 0; k < 20; ++k){
        int a = yb - 32 + 4 * k;
        if (a >= 0 && a <= 252){
          float4 cv = *(const float4*)(cq + a);
          if (c < 3){
            float4 tv = *(const float4*)(tcol + a);
            cv.x *= tv.x; cv.y *= tv.y; cv.z *= tv.z; cv.w *= tv.w;
          }
          w[4 * k] = cv.x; w[4 * k + 1] = cv.y; w[4 * k + 2] = cv.z; w[4 * k + 3] = cv.w;
        } else {
          #pragma unroll
          for (int d = 0; d < 4; ++d){
            int rr = refl(a + d);
            float v = cq[rr];
            if (c < 3) v *= tcol[rr];
            w[4 * k + d] = v;
          }
        }
      }
      #pragma unroll
      for (int u = 0; u < 64; u += 4){
        float k0 = bl[u * 10 + i],       k1 = bl[(u + 1) * 10 + i],
              k2 = bl[(u + 2) * 10 + i], k3 = bl[(u + 3) * 10 + i];
        #pragma unroll
        for (int r = 0; r < 16; ++r)
          acc[r] += k0 * w[u + r] + k1 * w[u + r + 1] + k2 * w[u + r + 2] + k3 * w[u + r + 3];
      }
      float k64 = bl[640 + i];
      #pragma unroll
      for (int r = 0; r < 16; ++r) acc[r] += k64 * w[64 + r];
    }
    float* So = ST + (c * 10 + j) * HW + x * 256 + yb;
    #pragma unroll
    for (int q = 0; q < 4; ++q){
      float4 res = {acc[4 * q], acc[4 * q + 1], acc[4 * q + 2], acc[4 * q + 3]};
      *(float4*)(So + 4 * q) = res;
    }
  } else {
    int b2 = bid - 640;
    int c = b2 >> 4, s = b2 & 15;
    int x = s * 16 + tx;
    const float* tcol = tiltT + c * HW + x * 256;
    float w[80];
    #pragma unroll
    for (int k = 0; k < 20; ++k){
      int a = yb - 32 + 4 * k;
      if (a >= 0 && a <= 252){
        float4 tv = *(const float4*)(tcol + a);
        w[4 * k] = tv.x; w[4 * k + 1] = tv.y; w[4 * k + 2] = tv.z; w[4 * k + 3] = tv.w;
      } else {
        #pragma unroll
        for (int d = 0; d < 4; ++d) w[4 * k + d] = tcol[refl(a + d)];
      }
    }
    for (int m = 0; m < 10; ++m){
      float acc[16];
      #pragma unroll
      for (int r = 0; r < 16; ++r) acc[r] = 0.f;
      #pragma unroll
      for (int u = 0; u < 64; u += 4){
        float k0 = mu[u * 10 + m],       k1 = mu[(u + 1) * 10 + m],
              k2 = mu[(u + 2) * 10 + m], k3 = mu[(u + 3) * 10 + m];
        #pragma unroll
        for (int r = 0; r < 16; ++r)
          acc[r] += k0 * w[u + r] + k1 * w[u + r + 1] + k2 * w[u + r + 2] + k3 * w[u + r + 3];
      }
      float k64 = mu[640 + m];
      #pragma unroll
      for (int r = 0; r < 16; ++r) acc[r] += k64 * w[64 + r];
      float* So = STmu + (c * 10 + m) * HW + x * 256 + yb;
      #pragma unroll
      for (int q = 0; q < 4; ++q){
        float4 res = {acc[4 * q], acc[4 * q + 1], acc[4 * q + 2], acc[4 * q + 3]};
        *(float4*)(So + 4 * q) = res;
      }
    }
  }
}

// ---------------- K4 v6: horizontal conv from TRANSPOSED ST via LDS transpose -----------
// grid 14 grps x 16 ytiles. Thread (yy = tid&15, xt = tid>>4) -> out rows y0+yy, x-tile xt.
// LDS row stride 325 (odd): compute reads are 2-way (free).
#define HYS 325
__global__ __launch_bounds__(256) void k_hconv6(const float* __restrict__ ST,
    const float* __restrict__ STmu, const float* __restrict__ br,
    const float* __restrict__ mu, float* __restrict__ part){
  __shared__ float sy[16 * HYS];
  int tid = threadIdx.x;
  int grp = blockIdx.x >> 4;
  int yt  = blockIdx.x & 15;
  int y0 = yt * 16;
  int yy = tid & 15, xt = tid >> 4;
  int isbr = (grp < 8);
  int tgt, h;
  if (isbr){ tgt = grp >> 1; h = grp & 1; }
  else     { int g2 = grp - 8; tgt = g2 >> 1; h = g2 & 1; }
  const float* kp   = isbr ? br : mu;
  const float* base = (isbr ? ST : STmu) + tgt * 10 * HW;
  float acc[16];
  #pragma unroll
  for (int r = 0; r < 16; ++r) acc[r] = 0.f;
  for (int p = 0; p < 5; ++p){
    int col = h * 5 + p;
    const float* plane = base + col * HW;
    __syncthreads();
    for (int e = tid; e < 1024; e += 256){
      int xg = e >> 2, q = e & 3;
      float4 v = *(const float4*)(plane + xg * 256 + y0 + q * 4);
      sy[(q * 4 + 0) * HYS + 32 + xg] = v.x;
      sy[(q * 4 + 1) * HYS + 32 + xg] = v.y;
      sy[(q * 4 + 2) * HYS + 32 + xg] = v.z;
      sy[(q * 4 + 3) * HYS + 32 + xg] = v.w;
    }
    for (int e = tid; e < 1024; e += 256){
      int pi = e >> 4, y2 = e & 15;
      int pos = (pi < 32) ? pi : (256 + pi);
      int xs  = (pi < 32) ? (32 - pos) : (542 - pos);
      sy[y2 * HYS + pos] = plane[xs * 256 + y0 + y2];
    }
    __syncthreads();
    const float* row = sy + yy * HYS + xt * 16;
    float w[80];
    #pragma unroll
    for (int t = 0; t < 80; ++t) w[t] = row[t];
    #pragma unroll
    for (int u = 0; u < 64; u += 4){
      float k0 = kp[u * 10 + col],       k1 = kp[(u + 1) * 10 + col],
            k2 = kp[(u + 2) * 10 + col], k3 = kp[(u + 3) * 10 + col];
      #pragma unroll
      for (int r = 0; r < 16; ++r)
        acc[r] += k0 * w[u + r] + k1 * w[u + r + 1] + k2 * w[u + r + 2] + k3 * w[u + r + 3];
    }
    float k64 = kp[640 + col];
    #pragma unroll
    for (int r = 0; r < 16; ++r) acc[r] += k64 * w[64 + r];
  }
  float* dst = part + grp * HW + (y0 + yy) * 256 + xt * 16;
  #pragma unroll
  for (int q = 0; q < 4; ++q){
    float4 res = {acc[4 * q], acc[4 * q + 1], acc[4 * q + 2], acc[4 * q + 3]};
    *(float4*)(dst + 4 * q) = res;
  }
}

// ---------------- K5: out_c = (P2c+P2c+1+P8+2c+P9+2c) / (P6+P7+muC) ---------------------
__global__ __launch_bounds__(256) void k_final(const float* __restrict__ part,
                                               const float* __restrict__ mu,
                                               float* __restrict__ out){
  int pix = blockIdx.x * 256 + threadIdx.x;
  float muC = 0.f;
  #pragma unroll
  for (int m = 0; m < 10; ++m){
    float s = 0.f;
    for (int u = 0; u < 65; ++u) s += mu[u * 10 + m];
    muC += s * s;
  }
  float den = part[6 * HW + pix] + part[7 * HW + pix] + muC;
  float inv = 1.f / den;
  #pragma unroll
  for (int c = 0; c < 3; ++c){
    float num = part[(2 * c) * HW + pix] + part[(2 * c + 1) * HW + pix]
              + part[(8 + 2 * c) * HW + pix] + part[(9 + 2 * c) * HW + pix];
    out[c * HW + pix] = num * inv;
  }
}

extern "C" void kernel_launch(void* const* d_in, const int* in_sizes, int n_in,
                              void* d_out, int out_size, void* d_ws, size_t ws_size,
                              hipStream_t stream) {
  const float* img  = (const float*)d_in[0];
  const float* zern = (const float*)d_in[1];
  const float* w1   = (const float*)d_in[2];
  const float* b1   = (const float*)d_in[3];
  const float* w2   = (const float*)d_in[4];
  const float* b2   = (const float*)d_in[5];
  const float* w3   = (const float*)d_in[6];
  const float* b3   = (const float*)d_in[7];
  const float* bl   = (const float*)d_in[8];
  const float* br   = (const float*)d_in[9];
  const float* mu   = (const float*)d_in[10];
  float* out = (float*)d_out;

  float* w     = (float*)d_ws;
  float* tiltT = w;              // planes [0,3)   (transposed)
  float* coefT = w + 3 * HW;     // planes [3,103) (transposed); dead after vconv7
  float* part  = w + 3 * HW;     // planes [3,17): hconv partials (reuse coefT region)
  float* ST    = w + 103 * HW;   // planes [103,143) (transposed)
  float* STmu  = w + 143 * HW;   // planes [143,173) (transposed)
  unsigned short* wbf = (unsigned short*)ST; // bf16 weights, dead before vconv7 writes

  k_gridsample2<<<256, 256, 0, stream>>>(img, zern, tiltT);
  k_wcvt<<<332, 256, 0, stream>>>(w1, w2, w3, wbf);
  k_mlp<<<1024, 256, 0, stream>>>(zern, b1, b2, b3, wbf, coefT);
  k_vconv7<<<688, 256, 0, stream>>>(tiltT, coefT, bl, mu, ST, STmu);
  k_hconv6<<<224, 256, 0, stream>>>(ST, STmu, br, mu, part);
  k_final<<<256, 256, 0, stream>>>(part, mu, out);
}

// Round 10
// 239.564 us; speedup vs baseline: 1.9055x; 1.9055x over previous
//
#include <hip/hip_runtime.h>

#define HW 65536

typedef __attribute__((ext_vector_type(8))) short short8;
typedef __attribute__((ext_vector_type(4))) float float4v;

__device__ __forceinline__ int refl(int i){ if (i < 0) i = -i; if (i > 255) i = 510 - i; return i; }
__device__ __forceinline__ float lrelu(float x){ return x > 0.f ? x : 0.01f * x; }
__device__ __forceinline__ unsigned short f2bf(float x){
  union { float f; unsigned int u; } v; v.f = x;
  unsigned int r = v.u + 0x7fff + ((v.u >> 16) & 1);
  return (unsigned short)(r >> 16);
}

// ---------------- K1: bilinear grid sample (border, align_corners=False) ----------------
__global__ __launch_bounds__(256) void k_gridsample(const float* __restrict__ img,
                                                    const float* __restrict__ zern,
                                                    float* __restrict__ tilt){
  int x = threadIdx.x, y = blockIdx.x;
  int pix = y * 256 + x;
  float px = zern[pix * 35 + 0], py = zern[pix * 35 + 1];
  float ix = ((float)x + px) * (256.f / 255.f) - 0.5f;
  float iy = ((float)y + py) * (256.f / 255.f) - 0.5f;
  ix = fminf(fmaxf(ix, 0.f), 255.f);
  iy = fminf(fmaxf(iy, 0.f), 255.f);
  float x0f = floorf(ix), y0f = floorf(iy);
  float wx = ix - x0f, wy = iy - y0f;
  int x0 = (int)x0f, y0 = (int)y0f;
  int x1 = min(x0 + 1, 255), y1 = min(y0 + 1, 255);
  #pragma unroll
  for (int c = 0; c < 3; ++c){
    const float* im = img + c * HW;
    float g00 = im[y0 * 256 + x0], g01 = im[y0 * 256 + x1];
    float g10 = im[y1 * 256 + x0], g11 = im[y1 * 256 + x1];
    float top = g00 * (1.f - wx) + g01 * wx;
    float bot = g10 * (1.f - wx) + g11 * wx;
    tilt[c * HW + pix] = top * (1.f - wy) + bot * wy;
  }
}

// ---------------- Weight convert: fp32 -> zero-padded bf16 ------------------------------
#define W2OFF 13312
#define W3OFF 59904
__global__ __launch_bounds__(256) void k_wcvt(const float* __restrict__ w1,
    const float* __restrict__ w2, const float* __restrict__ w3,
    unsigned short* __restrict__ wbf){
  int i = blockIdx.x * 256 + threadIdx.x;
  if (i < 208 * 64){
    int n = i >> 6, k = i & 63;
    float v = (n < 200 && k < 33) ? w1[n * 33 + k] : 0.f;
    wbf[i] = f2bf(v);
  } else if (i < W2OFF + 208 * 224){
    int j = i - W2OFF; int n = j / 224, k = j - n * 224;
    float v = (n < 200 && k < 200) ? w2[n * 200 + k] : 0.f;
    wbf[i] = f2bf(v);
  } else if (i < 84992){
    int j = i - W3OFF; int n = j / 224, k = j - n * 224;
    float v = (n < 100 && k < 200) ? w3[n * 200 + k] : 0.f;
    wbf[i] = f2bf(v);
  }
}

// ---------------- Fused MLP: 64-pixel tile, 3 layers, MFMA bf16 -------------------------
#define HSTR 232
__global__ __launch_bounds__(256, 1) void k_mlp(const float* __restrict__ zern,
    const float* __restrict__ b1f, const float* __restrict__ b2f,
    const float* __restrict__ b3f, const unsigned short* __restrict__ wbf,
    float* __restrict__ coefp){
  __shared__ char smem[59392];
  unsigned short* H1 = (unsigned short*)smem;
  float*          H3 = (float*)smem;
  unsigned short* XB = (unsigned short*)(smem + 29696);
  unsigned short* H2 = XB;
  int tid = threadIdx.x;
  int pix0 = blockIdx.x * 64;
  int lane = tid & 63, wv = tid >> 6;
  int ln = lane & 15, qd = lane >> 4;

  for (int e = tid; e < 2304; e += 256) ((int*)XB)[e] = 0;
  for (int e = tid; e < 768; e += 256){
    int m = e / 12, j = e - m * 12;
    ((int*)H1)[m * 116 + 104 + j] = 0;
  }
  __syncthreads();
  for (int e = tid; e < 64 * 33; e += 256){
    int m = e / 33, k = e - m * 33;
    XB[m * 72 + k] = f2bf(zern[(pix0 + m) * 35 + 2 + k]);
  }
  __syncthreads();

  // ---- layer 1 ----
  for (int nt = wv; nt < 13; nt += 4){
    int n = nt * 16 + ln;
    short8 b0 = *(const short8*)(wbf + n * 64 + qd * 8);
    short8 b1 = *(const short8*)(wbf + n * 64 + 32 + qd * 8);
    float bv = (n < 200) ? b1f[n] : 0.f;
    #pragma unroll
    for (int mt = 0; mt < 4; ++mt){
      float4v acc = {bv, bv, bv, bv};
      short8 a0 = *(const short8*)(XB + (mt * 16 + ln) * 72 + qd * 8);
      short8 a1 = *(const short8*)(XB + (mt * 16 + ln) * 72 + 32 + qd * 8);
      acc = __builtin_amdgcn_mfma_f32_16x16x32_bf16(a0, b0, acc, 0, 0, 0);
      acc = __builtin_amdgcn_mfma_f32_16x16x32_bf16(a1, b1, acc, 0, 0, 0);
      #pragma unroll
      for (int r = 0; r < 4; ++r)
        H1[(mt * 16 + qd * 4 + r) * HSTR + n] = f2bf(lrelu(acc[r]));
    }
  }
  __syncthreads();

  // ---- layer 2 ----
  for (int e = tid; e < 768; e += 256){
    int m = e / 12, j = e - m * 12;
    ((int*)H2)[m * 116 + 104 + j] = 0;
  }
  {
    const unsigned short* w2p = wbf + W2OFF;
    for (int nt = wv; nt < 13; nt += 4){
      int n = nt * 16 + ln;
      short8 bf[7];
      #pragma unroll
      for (int kc = 0; kc < 7; ++kc)
        bf[kc] = *(const short8*)(w2p + n * 224 + kc * 32 + qd * 8);
      float bv = (n < 200) ? b2f[n] : 0.f;
      #pragma unroll
      for (int mt = 0; mt < 4; ++mt){
        float4v acc = {bv, bv, bv, bv};
        #pragma unroll
        for (int kc = 0; kc < 7; ++kc){
          short8 af = *(const short8*)(H1 + (mt * 16 + ln) * HSTR + kc * 32 + qd * 8);
          acc = __builtin_amdgcn_mfma_f32_16x16x32_bf16(af, bf[kc], acc, 0, 0, 0);
        }
        #pragma unroll
        for (int r = 0; r < 4; ++r)
          H2[(mt * 16 + qd * 4 + r) * HSTR + n] = f2bf(lrelu(acc[r]));
      }
    }
  }
  __syncthreads();

  // ---- layer 3 ----
  {
    const unsigned short* w3p = wbf + W3OFF;
    for (int nt = wv; nt < 7; nt += 4){
      int n = nt * 16 + ln;
      short8 bf[7];
      #pragma unroll
      for (int kc = 0; kc < 7; ++kc)
        bf[kc] = *(const short8*)(w3p + n * 224 + kc * 32 + qd * 8);
      float bv = (n < 100) ? b3f[n] : 0.f;
      #pragma unroll
      for (int mt = 0; mt < 4; ++mt){
        float4v acc = {bv, bv, bv, bv};
        #pragma unroll
        for (int kc = 0; kc < 7; ++kc){
          short8 af = *(const short8*)(H2 + (mt * 16 + ln) * HSTR + kc * 32 + qd * 8);
          acc = __builtin_amdgcn_mfma_f32_16x16x32_bf16(af, bf[kc], acc, 0, 0, 0);
        }
        #pragma unroll
        for (int r = 0; r < 4; ++r)
          H3[(mt * 16 + qd * 4 + r) * 113 + n] = acc[r];
      }
    }
  }
  __syncthreads();

  for (int e = tid; e < 100 * 64; e += 256){
    int n = e >> 6, m = e & 63;
    coefp[n * HW + pix0 + m] = H3[m * 113 + n];
  }
}

// ---------------- vertical conv pass: rolling 20-float register ring, 8 outputs ---------
// col: LDS column (rows contiguous, 16B-aligned base). acc[r] += sum_u kv[u*10]*col[u+r].
__device__ __forceinline__ void vpass8(const float* __restrict__ col,
                                       const float* __restrict__ kv, float acc[8]){
  float w[20];
  #pragma unroll
  for (int k = 0; k < 5; ++k){
    float4 v = *(const float4*)(col + 4 * k);
    w[4 * k] = v.x; w[4 * k + 1] = v.y; w[4 * k + 2] = v.z; w[4 * k + 3] = v.w;
  }
  #pragma unroll
  for (int u = 0; u < 64; u += 4){
    float k0 = kv[u * 10], k1 = kv[(u + 1) * 10], k2 = kv[(u + 2) * 10], k3 = kv[(u + 3) * 10];
    #pragma unroll
    for (int r = 0; r < 8; ++r)
      acc[r] += k0 * w[(u + r) % 20] + k1 * w[(u + r + 1) % 20]
              + k2 * w[(u + r + 2) % 20] + k3 * w[(u + r + 3) % 20];
    if (u < 52){
      float4 v = *(const float4*)(col + u + 20);
      int b = u % 20;
      w[b] = v.x; w[b + 1] = v.y; w[b + 2] = v.z; w[b + 3] = v.w;
    }
  }
  float k64 = kv[640];
  #pragma unroll
  for (int r = 0; r < 8; ++r) acc[r] += k64 * w[(64 + r) % 20];
}

// ---------------- K3 v8: vertical conv, full-height 8-col strips (grid 1472) ------------
// bid < 1280: (c 0..3, j 0..9, s 0..31): S_{c,j} = sum_i vconv(X_{c,i10+j}, L_i) -> sbuf
// bid >= 1280: (c 0..2, s 0..31): Smu_{c,m} = vconv(tilt_c, mu_m), m = 0..9 -> smu
// 8-col strips double the grid vs R8 (2.7 -> 5.75 blocks/CU) with no extra global traffic
// (vertical conv: no horizontal halo). Natural VGPR allocation (see R7 spill lesson).
#define VSTR 324
__global__ __launch_bounds__(256) void k_vconv8(const float* __restrict__ tilt,
    const float* __restrict__ coefp, const float* __restrict__ bl,
    const float* __restrict__ mu, float* __restrict__ sbuf,
    float* __restrict__ smu){
  __shared__ __align__(16) float sx[8 * VSTR];
  int tid = threadIdx.x;
  int bid = blockIdx.x;
  int tx = tid & 7, yg = tid >> 3;
  int yb = yg * 8;

  // staging slots: 640 float4-slots (320 rows x 2 half-rows of 4 cols)
  int row0 = tid >> 1,         xh0 = tid & 1;
  int row1 = (tid + 256) >> 1, xh1 = tid & 1;       // (tid+256)&1 == tid&1
  int row2 = (tid + 512) >> 1, xh2 = tid & 1;
  bool has2 = (tid < 128);
  int g0 = refl(row0 - 32) * 256 + xh0 * 4;
  int g1 = refl(row1 - 32) * 256 + xh1 * 4;
  int g2 = refl(row2 - 32) * 256 + xh2 * 4;

  if (bid < 1280){
    int s = bid & 31;
    int cj = bid >> 5;
    int c = cj / 10, j = cj - c * 10;
    int x0 = s * 8;
    float4 t0v = {0,0,0,0}, t1v = {0,0,0,0}, t2v = {0,0,0,0};
    if (c < 3){
      const float* tc = tilt + c * HW + x0;
      t0v = *(const float4*)(tc + g0);
      t1v = *(const float4*)(tc + g1);
      if (has2) t2v = *(const float4*)(tc + g2);
    }
    float4 p0, p1, p2 = {0,0,0,0};
    {
      const float* cq = coefp + j * HW + x0;
      p0 = *(const float4*)(cq + g0);
      p1 = *(const float4*)(cq + g1);
      if (has2) p2 = *(const float4*)(cq + g2);
    }
    float acc[8];
    #pragma unroll
    for (int r = 0; r < 8; ++r) acc[r] = 0.f;
    for (int i = 0; i < 10; ++i){
      __syncthreads();
      float4 v0 = p0, v1 = p1, v2 = p2;
      if (c < 3){
        v0.x *= t0v.x; v0.y *= t0v.y; v0.z *= t0v.z; v0.w *= t0v.w;
        v1.x *= t1v.x; v1.y *= t1v.y; v1.z *= t1v.z; v1.w *= t1v.w;
        v2.x *= t2v.x; v2.y *= t2v.y; v2.z *= t2v.z; v2.w *= t2v.w;
      }
      {
        int b0 = (xh0 * 4) * VSTR + row0;
        sx[b0] = v0.x; sx[b0 + VSTR] = v0.y; sx[b0 + 2 * VSTR] = v0.z; sx[b0 + 3 * VSTR] = v0.w;
        int b1 = (xh1 * 4) * VSTR + row1;
        sx[b1] = v1.x; sx[b1 + VSTR] = v1.y; sx[b1 + 2 * VSTR] = v1.z; sx[b1 + 3 * VSTR] = v1.w;
        if (has2){
          int b2 = (xh2 * 4) * VSTR + row2;
          sx[b2] = v2.x; sx[b2 + VSTR] = v2.y; sx[b2 + 2 * VSTR] = v2.z; sx[b2 + 3 * VSTR] = v2.w;
        }
      }
      __syncthreads();
      if (i < 9){
        const float* cn = coefp + ((i + 1) * 10 + j) * HW + x0;
        p0 = *(const float4*)(cn + g0);
        p1 = *(const float4*)(cn + g1);
        if (has2) p2 = *(const float4*)(cn + g2);
      }
      vpass8(sx + tx * VSTR + yb, bl + i, acc);
    }
    float* S = sbuf + (c * 10 + j) * HW + x0 + tx;
    #pragma unroll
    for (int r = 0; r < 8; ++r)
      S[(yb + r) * 256] = acc[r];
  } else {
    int b2i = bid - 1280;
    int c = b2i >> 5;
    int s = b2i & 31;
    int x0 = s * 8;
    const float* tc = tilt + c * HW + x0;
    {
      float4 v0 = *(const float4*)(tc + g0);
      float4 v1 = *(const float4*)(tc + g1);
      int b0 = (xh0 * 4) * VSTR + row0;
      sx[b0] = v0.x; sx[b0 + VSTR] = v0.y; sx[b0 + 2 * VSTR] = v0.z; sx[b0 + 3 * VSTR] = v0.w;
      int b1 = (xh1 * 4) * VSTR + row1;
      sx[b1] = v1.x; sx[b1 + VSTR] = v1.y; sx[b1 + 2 * VSTR] = v1.z; sx[b1 + 3 * VSTR] = v1.w;
      if (has2){
        float4 v2 = *(const float4*)(tc + g2);
        int b2 = (xh2 * 4) * VSTR + row2;
        sx[b2] = v2.x; sx[b2 + VSTR] = v2.y; sx[b2 + 2 * VSTR] = v2.z; sx[b2 + 3 * VSTR] = v2.w;
      }
    }
    __syncthreads();
    const float* col = sx + tx * VSTR + yb;
    for (int m = 0; m < 10; ++m){
      float acc[8];
      #pragma unroll
      for (int r = 0; r < 8; ++r) acc[r] = 0.f;
      vpass8(col, mu + m, acc);
      float* S = smu + (c * 10 + m) * HW + x0 + tx;
      #pragma unroll
      for (int r = 0; r < 8; ++r)
        S[(yb + r) * 256] = acc[r];
    }
  }
}

// ---------------- K4 v5: horizontal conv, 14 groups x 64 y-tiles ------------------------
// grp 0..7:  (tgt 0..3, half h): sum_{j in [5h,5h+5)} hconv(S_{tgt,j}, R_j)   -> part[grp]
// grp 8..13: (tgt 0..2, half h): sum_{m in [5h,5h+5)} hconv(Smu_{tgt,m}, mu_m) -> part[grp]
__global__ __launch_bounds__(256) void k_hconv5(const float* __restrict__ sbuf,
    const float* __restrict__ smu, const float* __restrict__ br,
    const float* __restrict__ mu, float* __restrict__ part){
  __shared__ __align__(16) float sr[4][320];
  int tid = threadIdx.x;
  int grp = blockIdx.x >> 6;
  int yt = blockIdx.x & 63;
  int r = tid >> 6, xg = tid & 63, x0 = xg * 4;
  int isbr = (grp < 8);
  int tgt, h;
  if (isbr){ tgt = grp >> 1; h = grp & 1; }
  else     { int g2 = grp - 8; tgt = g2 >> 1; h = g2 & 1; }
  const float* kp   = isbr ? br : mu;
  const float* base = isbr ? (sbuf + tgt * 10 * HW) : (smu + tgt * 10 * HW);
  float a0 = 0.f, a1 = 0.f, a2 = 0.f, a3 = 0.f;
  for (int p = 0; p < 5; ++p){
    int col = h * 5 + p;
    const float* plane = base + col * HW;
    __syncthreads();
    for (int e = tid; e < 1280; e += 256){
      int rr = e / 320, ii = e - rr * 320;
      sr[rr][ii] = plane[(yt * 4 + rr) * 256 + refl(ii - 32)];
    }
    __syncthreads();
    float4 av = *(const float4*)&sr[r][x0];
    for (int u = 0; u < 64; u += 4){
      float4 bv = *(const float4*)&sr[r][x0 + u + 4];
      float k0 = kp[u * 10 + col],       k1 = kp[(u + 1) * 10 + col],
            k2 = kp[(u + 2) * 10 + col], k3 = kp[(u + 3) * 10 + col];
      a0 += k0 * av.x + k1 * av.y + k2 * av.z + k3 * av.w;
      a1 += k0 * av.y + k1 * av.z + k2 * av.w + k3 * bv.x;
      a2 += k0 * av.z + k1 * av.w + k2 * bv.x + k3 * bv.y;
      a3 += k0 * av.w + k1 * bv.x + k2 * bv.y + k3 * bv.z;
      av = bv;
    }
    float k64 = kp[640 + col];
    a0 += k64 * av.x; a1 += k64 * av.y; a2 += k64 * av.z; a3 += k64 * av.w;
  }
  float4 res = {a0, a1, a2, a3};
  *(float4*)(part + grp * HW + (yt * 4 + r) * 256 + x0) = res;
}

// ---------------- K5: out_c = (P2c+P2c+1+P8+2c+P9+2c) / (P6+P7+muC) ---------------------
__global__ __launch_bounds__(256) void k_final(const float* __restrict__ part,
                                               const float* __restrict__ mu,
                                               float* __restrict__ out){
  int pix = blockIdx.x * 256 + threadIdx.x;
  float muC = 0.f;
  #pragma unroll
  for (int m = 0; m < 10; ++m){
    float s = 0.f;
    for (int u = 0; u < 65; ++u) s += mu[u * 10 + m];
    muC += s * s;
  }
  float den = part[6 * HW + pix] + part[7 * HW + pix] + muC;
  float inv = 1.f / den;
  #pragma unroll
  for (int c = 0; c < 3; ++c){
    float num = part[(2 * c) * HW + pix] + part[(2 * c + 1) * HW + pix]
              + part[(8 + 2 * c) * HW + pix] + part[(9 + 2 * c) * HW + pix];
    out[c * HW + pix] = num * inv;
  }
}

extern "C" void kernel_launch(void* const* d_in, const int* in_sizes, int n_in,
                              void* d_out, int out_size, void* d_ws, size_t ws_size,
                              hipStream_t stream) {
  const float* img  = (const float*)d_in[0];
  const float* zern = (const float*)d_in[1];
  const float* w1   = (const float*)d_in[2];
  const float* b1   = (const float*)d_in[3];
  const float* w2   = (const float*)d_in[4];
  const float* b2   = (const float*)d_in[5];
  const float* w3   = (const float*)d_in[6];
  const float* b3   = (const float*)d_in[7];
  const float* bl   = (const float*)d_in[8];
  const float* br   = (const float*)d_in[9];
  const float* mu   = (const float*)d_in[10];
  float* out = (float*)d_out;

  float* w     = (float*)d_ws;
  float* tilt  = w;              // planes [0,3)
  float* coefp = w + 3 * HW;     // planes [3,103); dead after vconv8
  float* part  = w + 3 * HW;     // planes [3,17): hconv partials (reuse coefp region)
  float* sbuf  = w + 103 * HW;   // planes [103,143)
  float* smu   = w + 143 * HW;   // planes [143,173)
  unsigned short* wbf = (unsigned short*)sbuf; // bf16 weights, dead before vconv8 writes

  k_gridsample<<<256, 256, 0, stream>>>(img, zern, tilt);
  k_wcvt<<<332, 256, 0, stream>>>(w1, w2, w3, wbf);
  k_mlp<<<1024, 256, 0, stream>>>(zern, b1, b2, b3, wbf, coefp);
  k_vconv8<<<1472, 256, 0, stream>>>(tilt, coefp, bl, mu, sbuf, smu);
  k_hconv5<<<896, 256, 0, stream>>>(sbuf, smu, br, mu, part);
  k_final<<<256, 256, 0, stream>>>(part, mu, out);
}

// Round 11
// 237.546 us; speedup vs baseline: 1.9217x; 1.0085x over previous
//
#include <hip/hip_runtime.h>

#define HW 65536

typedef __attribute__((ext_vector_type(8))) short short8;
typedef __attribute__((ext_vector_type(4))) float float4v;

__device__ __forceinline__ int refl(int i){ if (i < 0) i = -i; if (i > 255) i = 510 - i; return i; }
__device__ __forceinline__ float lrelu(float x){ return x > 0.f ? x : 0.01f * x; }
__device__ __forceinline__ unsigned short f2bf(float x){
  union { float f; unsigned int u; } v; v.f = x;
  unsigned int r = v.u + 0x7fff + ((v.u >> 16) & 1);
  return (unsigned short)(r >> 16);
}

// ---------------- K1: bilinear grid sample (border, align_corners=False) ----------------
__global__ __launch_bounds__(256) void k_gridsample(const float* __restrict__ img,
                                                    const float* __restrict__ zern,
                                                    float* __restrict__ tilt){
  int x = threadIdx.x, y = blockIdx.x;
  int pix = y * 256 + x;
  float px = zern[pix * 35 + 0], py = zern[pix * 35 + 1];
  float ix = ((float)x + px) * (256.f / 255.f) - 0.5f;
  float iy = ((float)y + py) * (256.f / 255.f) - 0.5f;
  ix = fminf(fmaxf(ix, 0.f), 255.f);
  iy = fminf(fmaxf(iy, 0.f), 255.f);
  float x0f = floorf(ix), y0f = floorf(iy);
  float wx = ix - x0f, wy = iy - y0f;
  int x0 = (int)x0f, y0 = (int)y0f;
  int x1 = min(x0 + 1, 255), y1 = min(y0 + 1, 255);
  #pragma unroll
  for (int c = 0; c < 3; ++c){
    const float* im = img + c * HW;
    float g00 = im[y0 * 256 + x0], g01 = im[y0 * 256 + x1];
    float g10 = im[y1 * 256 + x0], g11 = im[y1 * 256 + x1];
    float top = g00 * (1.f - wx) + g01 * wx;
    float bot = g10 * (1.f - wx) + g11 * wx;
    tilt[c * HW + pix] = top * (1.f - wy) + bot * wy;
  }
}

// ---------------- Weight convert: fp32 -> zero-padded bf16 ------------------------------
#define W2OFF 13312
#define W3OFF 59904
__global__ __launch_bounds__(256) void k_wcvt(const float* __restrict__ w1,
    const float* __restrict__ w2, const float* __restrict__ w3,
    unsigned short* __restrict__ wbf){
  int i = blockIdx.x * 256 + threadIdx.x;
  if (i < 208 * 64){
    int n = i >> 6, k = i & 63;
    float v = (n < 200 && k < 33) ? w1[n * 33 + k] : 0.f;
    wbf[i] = f2bf(v);
  } else if (i < W2OFF + 208 * 224){
    int j = i - W2OFF; int n = j / 224, k = j - n * 224;
    float v = (n < 200 && k < 200) ? w2[n * 200 + k] : 0.f;
    wbf[i] = f2bf(v);
  } else if (i < 84992){
    int j = i - W3OFF; int n = j / 224, k = j - n * 224;
    float v = (n < 100 && k < 200) ? w3[n * 200 + k] : 0.f;
    wbf[i] = f2bf(v);
  }
}

// ---------------- Fused MLP: 64-pixel tile, 3 layers, MFMA bf16 -------------------------
#define HSTR 232
__global__ __launch_bounds__(256, 1) void k_mlp(const float* __restrict__ zern,
    const float* __restrict__ b1f, const float* __restrict__ b2f,
    const float* __restrict__ b3f, const unsigned short* __restrict__ wbf,
    float* __restrict__ coefp){
  __shared__ char smem[59392];
  unsigned short* H1 = (unsigned short*)smem;
  float*          H3 = (float*)smem;
  unsigned short* XB = (unsigned short*)(smem + 29696);
  unsigned short* H2 = XB;
  int tid = threadIdx.x;
  int pix0 = blockIdx.x * 64;
  int lane = tid & 63, wv = tid >> 6;
  int ln = lane & 15, qd = lane >> 4;

  for (int e = tid; e < 2304; e += 256) ((int*)XB)[e] = 0;
  for (int e = tid; e < 768; e += 256){
    int m = e / 12, j = e - m * 12;
    ((int*)H1)[m * 116 + 104 + j] = 0;
  }
  __syncthreads();
  for (int e = tid; e < 64 * 33; e += 256){
    int m = e / 33, k = e - m * 33;
    XB[m * 72 + k] = f2bf(zern[(pix0 + m) * 35 + 2 + k]);
  }
  __syncthreads();

  // ---- layer 1 ----
  for (int nt = wv; nt < 13; nt += 4){
    int n = nt * 16 + ln;
    short8 b0 = *(const short8*)(wbf + n * 64 + qd * 8);
    short8 b1 = *(const short8*)(wbf + n * 64 + 32 + qd * 8);
    float bv = (n < 200) ? b1f[n] : 0.f;
    #pragma unroll
    for (int mt = 0; mt < 4; ++mt){
      float4v acc = {bv, bv, bv, bv};
      short8 a0 = *(const short8*)(XB + (mt * 16 + ln) * 72 + qd * 8);
      short8 a1 = *(const short8*)(XB + (mt * 16 + ln) * 72 + 32 + qd * 8);
      acc = __builtin_amdgcn_mfma_f32_16x16x32_bf16(a0, b0, acc, 0, 0, 0);
      acc = __builtin_amdgcn_mfma_f32_16x16x32_bf16(a1, b1, acc, 0, 0, 0);
      #pragma unroll
      for (int r = 0; r < 4; ++r)
        H1[(mt * 16 + qd * 4 + r) * HSTR + n] = f2bf(lrelu(acc[r]));
    }
  }
  __syncthreads();

  // ---- layer 2 ----
  for (int e = tid; e < 768; e += 256){
    int m = e / 12, j = e - m * 12;
    ((int*)H2)[m * 116 + 104 + j] = 0;
  }
  {
    const unsigned short* w2p = wbf + W2OFF;
    for (int nt = wv; nt < 13; nt += 4){
      int n = nt * 16 + ln;
      short8 bf[7];
      #pragma unroll
      for (int kc = 0; kc < 7; ++kc)
        bf[kc] = *(const short8*)(w2p + n * 224 + kc * 32 + qd * 8);
      float bv = (n < 200) ? b2f[n] : 0.f;
      #pragma unroll
      for (int mt = 0; mt < 4; ++mt){
        float4v acc = {bv, bv, bv, bv};
        #pragma unroll
        for (int kc = 0; kc < 7; ++kc){
          short8 af = *(const short8*)(H1 + (mt * 16 + ln) * HSTR + kc * 32 + qd * 8);
          acc = __builtin_amdgcn_mfma_f32_16x16x32_bf16(af, bf[kc], acc, 0, 0, 0);
        }
        #pragma unroll
        for (int r = 0; r < 4; ++r)
          H2[(mt * 16 + qd * 4 + r) * HSTR + n] = f2bf(lrelu(acc[r]));
      }
    }
  }
  __syncthreads();

  // ---- layer 3 ----
  {
    const unsigned short* w3p = wbf + W3OFF;
    for (int nt = wv; nt < 7; nt += 4){
      int n = nt * 16 + ln;
      short8 bf[7];
      #pragma unroll
      for (int kc = 0; kc < 7; ++kc)
        bf[kc] = *(const short8*)(w3p + n * 224 + kc * 32 + qd * 8);
      float bv = (n < 100) ? b3f[n] : 0.f;
      #pragma unroll
      for (int mt = 0; mt < 4; ++mt){
        float4v acc = {bv, bv, bv, bv};
        #pragma unroll
        for (int kc = 0; kc < 7; ++kc){
          short8 af = *(const short8*)(H2 + (mt * 16 + ln) * HSTR + kc * 32 + qd * 8);
          acc = __builtin_amdgcn_mfma_f32_16x16x32_bf16(af, bf[kc], acc, 0, 0, 0);
        }
        #pragma unroll
        for (int r = 0; r < 4; ++r)
          H3[(mt * 16 + qd * 4 + r) * 113 + n] = acc[r];
      }
    }
  }
  __syncthreads();

  for (int e = tid; e < 100 * 64; e += 256){
    int n = e >> 6, m = e & 63;
    coefp[n * HW + pix0 + m] = H3[m * 113 + n];
  }
}

// ---------------- vertical conv pass: rolling 20-float register ring --------------------
__device__ __forceinline__ void vpass(const float* __restrict__ col,
                                      const float* __restrict__ kv, float acc[16]){
  float w[20];
  #pragma unroll
  for (int k = 0; k < 5; ++k){
    float4 v = *(const float4*)(col + 4 * k);
    w[4 * k] = v.x; w[4 * k + 1] = v.y; w[4 * k + 2] = v.z; w[4 * k + 3] = v.w;
  }
  #pragma unroll
  for (int u = 0; u < 64; u += 4){
    float k0 = kv[u * 10], k1 = kv[(u + 1) * 10], k2 = kv[(u + 2) * 10], k3 = kv[(u + 3) * 10];
    #pragma unroll
    for (int r = 0; r < 16; ++r)
      acc[r] += k0 * w[(u + r) % 20] + k1 * w[(u + r + 1) % 20]
              + k2 * w[(u + r + 2) % 20] + k3 * w[(u + r + 3) % 20];
    if (u < 60){
      float4 v = *(const float4*)(col + u + 20);
      int b = u % 20;
      w[b] = v.x; w[b + 1] = v.y; w[b + 2] = v.z; w[b + 3] = v.w;
    }
  }
  float k64 = kv[640];
  #pragma unroll
  for (int r = 0; r < 16; ++r) acc[r] += k64 * w[(64 + r) % 20];
}

// ---------------- K3 v9: full-height 16-col strips, i-SPLIT (5 i per block) -------------
// bid < 1280: (c 0..3, j 0..9, ih 0..1, s 0..15): partial S over i in [5ih, 5ih+5)
//             -> (ih ? sbufB : sbufA). Full height: no halo duplication; coef planes are
//             read only by their own half -> FETCH stays ~vconv6 level; grid 2x (R10 fix:
//             occupancy from the i axis, NOT 8-col strips which broke cache-line economy).
// bid >= 1280: (c 0..2, s): Smu_{c,m} = vconv(tilt_c, mu_m), m = 0..9 -> smu
#define VSTR 324
__global__ __launch_bounds__(256) void k_vconv9(const float* __restrict__ tilt,
    const float* __restrict__ coefp, const float* __restrict__ bl,
    const float* __restrict__ mu, float* __restrict__ sbufA,
    float* __restrict__ sbufB, float* __restrict__ smu){
  __shared__ __align__(16) float sx[16 * VSTR];
  int tid = threadIdx.x;
  int bid = blockIdx.x;
  int tx = tid & 15, yg = tid >> 4;
  int yb = yg * 16;
  int t0 = tid >> 2, xq = tid & 3;

  int offs[5];
  #pragma unroll
  for (int k = 0; k < 5; ++k)
    offs[k] = refl(t0 + k * 64 - 32) * 256 + xq * 4;

  if (bid < 1280){
    int s = bid & 15;
    int t = bid >> 4;            // 0..79
    int c = t / 20;
    int rem = t - c * 20;
    int j = rem >> 1, ih = rem & 1;
    int i0 = ih * 5;
    int x0 = s * 16;
    float4 treg[5];
    if (c < 3){
      const float* tc = tilt + c * HW + x0;
      #pragma unroll
      for (int k = 0; k < 5; ++k) treg[k] = *(const float4*)(tc + offs[k]);
    }
    float4 pf[5];
    {
      const float* cq = coefp + (i0 * 10 + j) * HW + x0;
      #pragma unroll
      for (int k = 0; k < 5; ++k) pf[k] = *(const float4*)(cq + offs[k]);
    }
    float acc[16];
    #pragma unroll
    for (int r = 0; r < 16; ++r) acc[r] = 0.f;
    for (int ii = 0; ii < 5; ++ii){
      int i = i0 + ii;
      __syncthreads();
      #pragma unroll
      for (int k = 0; k < 5; ++k){
        float4 v = pf[k];
        if (c < 3){ v.x *= treg[k].x; v.y *= treg[k].y; v.z *= treg[k].z; v.w *= treg[k].w; }
        int base = (xq * 4) * VSTR + t0 + k * 64;
        sx[base] = v.x; sx[base + VSTR] = v.y; sx[base + 2 * VSTR] = v.z; sx[base + 3 * VSTR] = v.w;
      }
      __syncthreads();
      if (ii < 4){
        const float* cn = coefp + ((i + 1) * 10 + j) * HW + x0;
        #pragma unroll
        for (int k = 0; k < 5; ++k) pf[k] = *(const float4*)(cn + offs[k]);
      }
      vpass(sx + tx * VSTR + yb, bl + i, acc);
    }
    float* S = (ih ? sbufB : sbufA) + (c * 10 + j) * HW;
    #pragma unroll
    for (int r = 0; r < 16; ++r)
      S[(yb + r) * 256 + x0 + tx] = acc[r];
  } else {
    int b2 = bid - 1280;
    int c = b2 >> 4;
    int s = b2 & 15;
    int x0 = s * 16;
    const float* tc = tilt + c * HW + x0;
    #pragma unroll
    for (int k = 0; k < 5; ++k){
      float4 v = *(const float4*)(tc + offs[k]);
      int base = (xq * 4) * VSTR + t0 + k * 64;
      sx[base] = v.x; sx[base + VSTR] = v.y; sx[base + 2 * VSTR] = v.z; sx[base + 3 * VSTR] = v.w;
    }
    __syncthreads();
    const float* col = sx + tx * VSTR + yb;
    for (int m = 0; m < 10; ++m){
      float acc[16];
      #pragma unroll
      for (int r = 0; r < 16; ++r) acc[r] = 0.f;
      vpass(col, mu + m, acc);
      float* S = smu + (c * 10 + m) * HW;
      #pragma unroll
      for (int r = 0; r < 16; ++r)
        S[(yb + r) * 256 + x0 + tx] = acc[r];
    }
  }
}

// ---------------- K4: horizontal conv, 14 groups x 64 y-tiles, A+B partial sum ----------
// grp 0..7:  (tgt 0..3, half h): sum_{j in [5h,5h+5)} hconv(A_{tgt,j}+B_{tgt,j}, R_j) -> part
// grp 8..13: (tgt 0..2, half h): sum_{m in [5h,5h+5)} hconv(Smu_{tgt,m}, mu_m)       -> part
__global__ __launch_bounds__(256) void k_hconv7(const float* __restrict__ sbufA,
    const float* __restrict__ sbufB, const float* __restrict__ smu,
    const float* __restrict__ br, const float* __restrict__ mu,
    float* __restrict__ part){
  __shared__ __align__(16) float sr[4][320];
  int tid = threadIdx.x;
  int grp = blockIdx.x >> 6;
  int yt = blockIdx.x & 63;
  int r = tid >> 6, xg = tid & 63, x0 = xg * 4;
  int isbr = (grp < 8);
  int tgt, h;
  if (isbr){ tgt = grp >> 1; h = grp & 1; }
  else     { int g2 = grp - 8; tgt = g2 >> 1; h = g2 & 1; }
  const float* kp = isbr ? br : mu;
  float a0 = 0.f, a1 = 0.f, a2 = 0.f, a3 = 0.f;
  for (int p = 0; p < 5; ++p){
    int col = h * 5 + p;
    __syncthreads();
    if (isbr){
      const float* pa = sbufA + (tgt * 10 + col) * HW;
      const float* pb = sbufB + (tgt * 10 + col) * HW;
      for (int e = tid; e < 1280; e += 256){
        int rr = e / 320, ii = e - rr * 320;
        int g = (yt * 4 + rr) * 256 + refl(ii - 32);
        sr[rr][ii] = pa[g] + pb[g];
      }
    } else {
      const float* pm = smu + (tgt * 10 + col) * HW;
      for (int e = tid; e < 1280; e += 256){
        int rr = e / 320, ii = e - rr * 320;
        sr[rr][ii] = pm[(yt * 4 + rr) * 256 + refl(ii - 32)];
      }
    }
    __syncthreads();
    float4 av = *(const float4*)&sr[r][x0];
    for (int u = 0; u < 64; u += 4){
      float4 bv = *(const float4*)&sr[r][x0 + u + 4];
      float k0 = kp[u * 10 + col],       k1 = kp[(u + 1) * 10 + col],
            k2 = kp[(u + 2) * 10 + col], k3 = kp[(u + 3) * 10 + col];
      a0 += k0 * av.x + k1 * av.y + k2 * av.z + k3 * av.w;
      a1 += k0 * av.y + k1 * av.z + k2 * av.w + k3 * bv.x;
      a2 += k0 * av.z + k1 * av.w + k2 * bv.x + k3 * bv.y;
      a3 += k0 * av.w + k1 * bv.x + k2 * bv.y + k3 * bv.z;
      av = bv;
    }
    float k64 = kp[640 + col];
    a0 += k64 * av.x; a1 += k64 * av.y; a2 += k64 * av.z; a3 += k64 * av.w;
  }
  float4 res = {a0, a1, a2, a3};
  *(float4*)(part + grp * HW + (yt * 4 + r) * 256 + x0) = res;
}

// ---------------- K5: out_c = (P2c+P2c+1+P8+2c+P9+2c) / (P6+P7+muC) ---------------------
__global__ __launch_bounds__(256) void k_final(const float* __restrict__ part,
                                               const float* __restrict__ mu,
                                               float* __restrict__ out){
  int pix = blockIdx.x * 256 + threadIdx.x;
  float muC = 0.f;
  #pragma unroll
  for (int m = 0; m < 10; ++m){
    float s = 0.f;
    for (int u = 0; u < 65; ++u) s += mu[u * 10 + m];
    muC += s * s;
  }
  float den = part[6 * HW + pix] + part[7 * HW + pix] + muC;
  float inv = 1.f / den;
  #pragma unroll
  for (int c = 0; c < 3; ++c){
    float num = part[(2 * c) * HW + pix] + part[(2 * c + 1) * HW + pix]
              + part[(8 + 2 * c) * HW + pix] + part[(9 + 2 * c) * HW + pix];
    out[c * HW + pix] = num * inv;
  }
}

extern "C" void kernel_launch(void* const* d_in, const int* in_sizes, int n_in,
                              void* d_out, int out_size, void* d_ws, size_t ws_size,
                              hipStream_t stream) {
  const float* img  = (const float*)d_in[0];
  const float* zern = (const float*)d_in[1];
  const float* w1   = (const float*)d_in[2];
  const float* b1   = (const float*)d_in[3];
  const float* w2   = (const float*)d_in[4];
  const float* b2   = (const float*)d_in[5];
  const float* w3   = (const float*)d_in[6];
  const float* b3   = (const float*)d_in[7];
  const float* bl   = (const float*)d_in[8];
  const float* br   = (const float*)d_in[9];
  const float* mu   = (const float*)d_in[10];
  float* out = (float*)d_out;

  float* w     = (float*)d_ws;
  float* tilt  = w;              // planes [0,3)
  float* coefp = w + 3 * HW;     // planes [3,103); dead after vconv9
  float* part  = w + 3 * HW;     // planes [3,17): hconv partials (reuse coefp region)
  float* sbufA = w + 103 * HW;   // planes [103,143)
  float* sbufB = w + 143 * HW;   // planes [143,183)
  float* smu   = w + 183 * HW;   // planes [183,213)
  unsigned short* wbf = (unsigned short*)sbufA; // bf16 weights, dead before vconv9 writes

  k_gridsample<<<256, 256, 0, stream>>>(img, zern, tilt);
  k_wcvt<<<332, 256, 0, stream>>>(w1, w2, w3, wbf);
  k_mlp<<<1024, 256, 0, stream>>>(zern, b1, b2, b3, wbf, coefp);
  k_vconv9<<<1328, 256, 0, stream>>>(tilt, coefp, bl, mu, sbufA, sbufB, smu);
  k_hconv7<<<896, 256, 0, stream>>>(sbufA, sbufB, smu, br, mu, part);
  k_final<<<256, 256, 0, stream>>>(part, mu, out);
}

// Round 12
// 184.048 us; speedup vs baseline: 2.4803x; 1.2907x over previous
//
#include <hip/hip_runtime.h>

#define HW 65536

typedef __attribute__((ext_vector_type(8))) short short8;
typedef __attribute__((ext_vector_type(4))) float float4v;

__device__ __forceinline__ int refl(int i){ if (i < 0) i = -i; if (i > 255) i = 510 - i; return i; }
__device__ __forceinline__ float lrelu(float x){ return x > 0.f ? x : 0.01f * x; }
__device__ __forceinline__ unsigned int f2bf(float x){
  union { float f; unsigned int u; } v; v.f = x;
  unsigned int r = v.u + 0x7fff + ((v.u >> 16) & 1);
  return r >> 16;
}

// ---------------- K1: bilinear grid sample (border, align_corners=False) ----------------
__global__ __launch_bounds__(256) void k_gridsample(const float* __restrict__ img,
                                                    const float* __restrict__ zern,
                                                    float* __restrict__ tilt){
  int x = threadIdx.x, y = blockIdx.x;
  int pix = y * 256 + x;
  float px = zern[pix * 35 + 0], py = zern[pix * 35 + 1];
  float ix = ((float)x + px) * (256.f / 255.f) - 0.5f;
  float iy = ((float)y + py) * (256.f / 255.f) - 0.5f;
  ix = fminf(fmaxf(ix, 0.f), 255.f);
  iy = fminf(fmaxf(iy, 0.f), 255.f);
  float x0f = floorf(ix), y0f = floorf(iy);
  float wx = ix - x0f, wy = iy - y0f;
  int x0 = (int)x0f, y0 = (int)y0f;
  int x1 = min(x0 + 1, 255), y1 = min(y0 + 1, 255);
  #pragma unroll
  for (int c = 0; c < 3; ++c){
    const float* im = img + c * HW;
    float g00 = im[y0 * 256 + x0], g01 = im[y0 * 256 + x1];
    float g10 = im[y1 * 256 + x0], g11 = im[y1 * 256 + x1];
    float top = g00 * (1.f - wx) + g01 * wx;
    float bot = g10 * (1.f - wx) + g11 * wx;
    tilt[c * HW + pix] = top * (1.f - wy) + bot * wy;
  }
}

// ---------------- Weight convert: fp32 -> zero-padded bf16 ------------------------------
#define W2OFF 13312
#define W3OFF 59904
__global__ __launch_bounds__(256) void k_wcvt(const float* __restrict__ w1,
    const float* __restrict__ w2, const float* __restrict__ w3,
    unsigned short* __restrict__ wbf){
  int i = blockIdx.x * 256 + threadIdx.x;
  if (i < 208 * 64){
    int n = i >> 6, k = i & 63;
    float v = (n < 200 && k < 33) ? w1[n * 33 + k] : 0.f;
    wbf[i] = (unsigned short)f2bf(v);
  } else if (i < W2OFF + 208 * 224){
    int j = i - W2OFF; int n = j / 224, k = j - n * 224;
    float v = (n < 200 && k < 200) ? w2[n * 200 + k] : 0.f;
    wbf[i] = (unsigned short)f2bf(v);
  } else if (i < 84992){
    int j = i - W3OFF; int n = j / 224, k = j - n * 224;
    float v = (n < 100 && k < 200) ? w3[n * 200 + k] : 0.f;
    wbf[i] = (unsigned short)f2bf(v);
  }
}

// ---------------- Toeplitz tables: Tt[t][m][k] = taps[k-m], t<10: bl col t; t>=10: mu ----
// 20 x 16 x 96 bf16 = 61 KB. A-operand of the banded-Toeplitz MFMA vconv.
__global__ __launch_bounds__(256) void k_tz(const float* __restrict__ bl,
    const float* __restrict__ mu, unsigned short* __restrict__ Tt){
  int e = blockIdx.x * 256 + threadIdx.x;
  if (e >= 30720) return;
  int t = e / 1536, rem = e - t * 1536;
  int m = rem / 96, k = rem - m * 96;
  int d = k - m;
  float v = 0.f;
  if (d >= 0 && d <= 64) v = (t < 10) ? bl[d * 10 + t] : mu[d * 10 + (t - 10)];
  Tt[e] = (unsigned short)f2bf(v);
}

// ---------------- Fused MLP: 64-pixel tile, 3 layers, MFMA bf16 -------------------------
#define HSTR 232
__global__ __launch_bounds__(256, 1) void k_mlp(const float* __restrict__ zern,
    const float* __restrict__ b1f, const float* __restrict__ b2f,
    const float* __restrict__ b3f, const unsigned short* __restrict__ wbf,
    float* __restrict__ coefp){
  __shared__ char smem[59392];
  unsigned short* H1 = (unsigned short*)smem;
  float*          H3 = (float*)smem;
  unsigned short* XB = (unsigned short*)(smem + 29696);
  unsigned short* H2 = XB;
  int tid = threadIdx.x;
  int pix0 = blockIdx.x * 64;
  int lane = tid & 63, wv = tid >> 6;
  int ln = lane & 15, qd = lane >> 4;

  for (int e = tid; e < 2304; e += 256) ((int*)XB)[e] = 0;
  for (int e = tid; e < 768; e += 256){
    int m = e / 12, j = e - m * 12;
    ((int*)H1)[m * 116 + 104 + j] = 0;
  }
  __syncthreads();
  for (int e = tid; e < 64 * 33; e += 256){
    int m = e / 33, k = e - m * 33;
    XB[m * 72 + k] = (unsigned short)f2bf(zern[(pix0 + m) * 35 + 2 + k]);
  }
  __syncthreads();

  // ---- layer 1 ----
  for (int nt = wv; nt < 13; nt += 4){
    int n = nt * 16 + ln;
    short8 b0 = *(const short8*)(wbf + n * 64 + qd * 8);
    short8 b1 = *(const short8*)(wbf + n * 64 + 32 + qd * 8);
    float bv = (n < 200) ? b1f[n] : 0.f;
    #pragma unroll
    for (int mt = 0; mt < 4; ++mt){
      float4v acc = {bv, bv, bv, bv};
      short8 a0 = *(const short8*)(XB + (mt * 16 + ln) * 72 + qd * 8);
      short8 a1 = *(const short8*)(XB + (mt * 16 + ln) * 72 + 32 + qd * 8);
      acc = __builtin_amdgcn_mfma_f32_16x16x32_bf16(a0, b0, acc, 0, 0, 0);
      acc = __builtin_amdgcn_mfma_f32_16x16x32_bf16(a1, b1, acc, 0, 0, 0);
      #pragma unroll
      for (int r = 0; r < 4; ++r)
        H1[(mt * 16 + qd * 4 + r) * HSTR + n] = (unsigned short)f2bf(lrelu(acc[r]));
    }
  }
  __syncthreads();

  // ---- layer 2 ----
  for (int e = tid; e < 768; e += 256){
    int m = e / 12, j = e - m * 12;
    ((int*)H2)[m * 116 + 104 + j] = 0;
  }
  {
    const unsigned short* w2p = wbf + W2OFF;
    for (int nt = wv; nt < 13; nt += 4){
      int n = nt * 16 + ln;
      short8 bf[7];
      #pragma unroll
      for (int kc = 0; kc < 7; ++kc)
        bf[kc] = *(const short8*)(w2p + n * 224 + kc * 32 + qd * 8);
      float bv = (n < 200) ? b2f[n] : 0.f;
      #pragma unroll
      for (int mt = 0; mt < 4; ++mt){
        float4v acc = {bv, bv, bv, bv};
        #pragma unroll
        for (int kc = 0; kc < 7; ++kc){
          short8 af = *(const short8*)(H1 + (mt * 16 + ln) * HSTR + kc * 32 + qd * 8);
          acc = __builtin_amdgcn_mfma_f32_16x16x32_bf16(af, bf[kc], acc, 0, 0, 0);
        }
        #pragma unroll
        for (int r = 0; r < 4; ++r)
          H2[(mt * 16 + qd * 4 + r) * HSTR + n] = (unsigned short)f2bf(lrelu(acc[r]));
      }
    }
  }
  __syncthreads();

  // ---- layer 3 ----
  {
    const unsigned short* w3p = wbf + W3OFF;
    for (int nt = wv; nt < 7; nt += 4){
      int n = nt * 16 + ln;
      short8 bf[7];
      #pragma unroll
      for (int kc = 0; kc < 7; ++kc)
        bf[kc] = *(const short8*)(w3p + n * 224 + kc * 32 + qd * 8);
      float bv = (n < 100) ? b3f[n] : 0.f;
      #pragma unroll
      for (int mt = 0; mt < 4; ++mt){
        float4v acc = {bv, bv, bv, bv};
        #pragma unroll
        for (int kc = 0; kc < 7; ++kc){
          short8 af = *(const short8*)(H2 + (mt * 16 + ln) * HSTR + kc * 32 + qd * 8);
          acc = __builtin_amdgcn_mfma_f32_16x16x32_bf16(af, bf[kc], acc, 0, 0, 0);
        }
        #pragma unroll
        for (int r = 0; r < 4; ++r)
          H3[(mt * 16 + qd * 4 + r) * 113 + n] = acc[r];
      }
    }
  }
  __syncthreads();

  for (int e = tid; e < 100 * 64; e += 256){
    int n = e >> 6, m = e & 63;
    coefp[n * HW + pix0 + m] = H3[m * 113 + n];
  }
}

// ---------------- K3 v10: vertical conv as banded-Toeplitz MFMA -------------------------
// D[16y x 16x] = A_i[16 x 96] . B[96 x 16x]; A_i = L_i Toeplitz (global, L2-hot),
// B = X window in column-major bf16 LDS (col*VB + row, rows 0..319 = y -32..287,
// rows 320..343 zeroed; band zero-padding makes the tail harmless).
// bid < 640: (c 0..3, j 0..9, s 0..15): S_{c,j} = Sum_i A_i . X_{c,i10+j}  (Sum_i in acc)
// bid >= 640: (c 0..2, s): Smu_{c,m} = A_mu_m . tilt_c, m = 0..9
#define VB 344
__global__ __launch_bounds__(256) void k_vconv10(const float* __restrict__ tilt,
    const float* __restrict__ coefp, const unsigned short* __restrict__ Tt,
    float* __restrict__ sbuf, float* __restrict__ smu){
  __shared__ __align__(16) unsigned short sxb[16 * VB];
  int tid = threadIdx.x;
  int bid = blockIdx.x;
  int lane = tid & 63, wv = tid >> 6;
  int ln = lane & 15, qd = lane >> 4;
  int col = tid & 15, seg = tid >> 4;
  int r0 = seg * 20;

  int goff[20];
  #pragma unroll
  for (int q = 0; q < 20; ++q) goff[q] = refl(r0 + q - 32) * 256 + col;

  // zero tail rows 320..343 (once)
  for (int e = tid; e < 384; e += 256){
    int cc = e / 24, rp = e - cc * 24;
    sxb[cc * VB + 320 + rp] = 0;
  }

  if (bid < 640){
    int s = bid & 15;
    int cj = bid >> 4;
    int c = cj / 10, j = cj - c * 10;
    int x0 = s * 16;
    float treg[20];
    if (c < 3){
      const float* tc = tilt + c * HW + x0;
      #pragma unroll
      for (int q = 0; q < 20; ++q) treg[q] = tc[goff[q]];
    }
    float pf[20];
    {
      const float* cq = coefp + j * HW + x0;
      #pragma unroll
      for (int q = 0; q < 20; ++q) pf[q] = cq[goff[q]];
    }
    float4v acc[4];
    #pragma unroll
    for (int t = 0; t < 4; ++t) acc[t] = (float4v){0.f, 0.f, 0.f, 0.f};
    for (int i = 0; i < 10; ++i){
      __syncthreads();
      #pragma unroll
      for (int q = 0; q < 10; ++q){
        float v0 = pf[2 * q], v1 = pf[2 * q + 1];
        if (c < 3){ v0 *= treg[2 * q]; v1 *= treg[2 * q + 1]; }
        unsigned int pk = f2bf(v0) | (f2bf(v1) << 16);
        *(unsigned int*)&sxb[col * VB + r0 + 2 * q] = pk;
      }
      __syncthreads();
      if (i < 9){
        const float* cn = coefp + ((i + 1) * 10 + j) * HW + x0;
        #pragma unroll
        for (int q = 0; q < 20; ++q) pf[q] = cn[goff[q]];
      }
      const unsigned short* ta = Tt + i * 1536 + ln * 96 + qd * 8;
      short8 A0 = *(const short8*)(ta);
      short8 A1 = *(const short8*)(ta + 32);
      short8 A2 = *(const short8*)(ta + 64);
      #pragma unroll
      for (int t = 0; t < 4; ++t){
        int yt = wv * 4 + t;
        const unsigned short* bp = sxb + ln * VB + yt * 16 + qd * 8;
        short8 B0 = *(const short8*)(bp);
        short8 B1 = *(const short8*)(bp + 32);
        short8 B2 = *(const short8*)(bp + 64);
        acc[t] = __builtin_amdgcn_mfma_f32_16x16x32_bf16(A0, B0, acc[t], 0, 0, 0);
        acc[t] = __builtin_amdgcn_mfma_f32_16x16x32_bf16(A1, B1, acc[t], 0, 0, 0);
        acc[t] = __builtin_amdgcn_mfma_f32_16x16x32_bf16(A2, B2, acc[t], 0, 0, 0);
      }
    }
    float* S = sbuf + (c * 10 + j) * HW + x0 + ln;
    #pragma unroll
    for (int t = 0; t < 4; ++t){
      int yt = wv * 4 + t;
      #pragma unroll
      for (int r = 0; r < 4; ++r)
        S[(yt * 16 + qd * 4 + r) * 256] = acc[t][r];
    }
  } else {
    int b2 = bid - 640;
    int c = b2 >> 4, s = b2 & 15;
    int x0 = s * 16;
    const float* tc = tilt + c * HW + x0;
    float tv[20];
    #pragma unroll
    for (int q = 0; q < 20; ++q) tv[q] = tc[goff[q]];
    #pragma unroll
    for (int q = 0; q < 10; ++q){
      unsigned int pk = f2bf(tv[2 * q]) | (f2bf(tv[2 * q + 1]) << 16);
      *(unsigned int*)&sxb[col * VB + r0 + 2 * q] = pk;
    }
    __syncthreads();
    for (int m = 0; m < 10; ++m){
      const unsigned short* ta = Tt + (10 + m) * 1536 + ln * 96 + qd * 8;
      short8 A0 = *(const short8*)(ta);
      short8 A1 = *(const short8*)(ta + 32);
      short8 A2 = *(const short8*)(ta + 64);
      float4v acc[4];
      #pragma unroll
      for (int t = 0; t < 4; ++t) acc[t] = (float4v){0.f, 0.f, 0.f, 0.f};
      #pragma unroll
      for (int t = 0; t < 4; ++t){
        int yt = wv * 4 + t;
        const unsigned short* bp = sxb + ln * VB + yt * 16 + qd * 8;
        short8 B0 = *(const short8*)(bp);
        short8 B1 = *(const short8*)(bp + 32);
        short8 B2 = *(const short8*)(bp + 64);
        acc[t] = __builtin_amdgcn_mfma_f32_16x16x32_bf16(A0, B0, acc[t], 0, 0, 0);
        acc[t] = __builtin_amdgcn_mfma_f32_16x16x32_bf16(A1, B1, acc[t], 0, 0, 0);
        acc[t] = __builtin_amdgcn_mfma_f32_16x16x32_bf16(A2, B2, acc[t], 0, 0, 0);
      }
      float* S = smu + (c * 10 + m) * HW + x0 + ln;
      #pragma unroll
      for (int t = 0; t < 4; ++t){
        int yt = wv * 4 + t;
        #pragma unroll
        for (int r = 0; r < 4; ++r)
          S[(yt * 16 + qd * 4 + r) * 256] = acc[t][r];
      }
    }
  }
}

// ---------------- K4: horizontal conv, 14 groups x 64 y-tiles (single sbuf) -------------
__global__ __launch_bounds__(256) void k_hconv5(const float* __restrict__ sbuf,
    const float* __restrict__ smu, const float* __restrict__ br,
    const float* __restrict__ mu, float* __restrict__ part){
  __shared__ __align__(16) float sr[4][320];
  int tid = threadIdx.x;
  int grp = blockIdx.x >> 6;
  int yt = blockIdx.x & 63;
  int r = tid >> 6, xg = tid & 63, x0 = xg * 4;
  int isbr = (grp < 8);
  int tgt, h;
  if (isbr){ tgt = grp >> 1; h = grp & 1; }
  else     { int g2 = grp - 8; tgt = g2 >> 1; h = g2 & 1; }
  const float* kp   = isbr ? br : mu;
  const float* base = isbr ? (sbuf + tgt * 10 * HW) : (smu + tgt * 10 * HW);
  float a0 = 0.f, a1 = 0.f, a2 = 0.f, a3 = 0.f;
  for (int p = 0; p < 5; ++p){
    int col = h * 5 + p;
    const float* plane = base + col * HW;
    __syncthreads();
    for (int e = tid; e < 1280; e += 256){
      int rr = e / 320, ii = e - rr * 320;
      sr[rr][ii] = plane[(yt * 4 + rr) * 256 + refl(ii - 32)];
    }
    __syncthreads();
    float4 av = *(const float4*)&sr[r][x0];
    for (int u = 0; u < 64; u += 4){
      float4 bv = *(const float4*)&sr[r][x0 + u + 4];
      float k0 = kp[u * 10 + col],       k1 = kp[(u + 1) * 10 + col],
            k2 = kp[(u + 2) * 10 + col], k3 = kp[(u + 3) * 10 + col];
      a0 += k0 * av.x + k1 * av.y + k2 * av.z + k3 * av.w;
      a1 += k0 * av.y + k1 * av.z + k2 * av.w + k3 * bv.x;
      a2 += k0 * av.z + k1 * av.w + k2 * bv.x + k3 * bv.y;
      a3 += k0 * av.w + k1 * bv.x + k2 * bv.y + k3 * bv.z;
      av = bv;
    }
    float k64 = kp[640 + col];
    a0 += k64 * av.x; a1 += k64 * av.y; a2 += k64 * av.z; a3 += k64 * av.w;
  }
  float4 res = {a0, a1, a2, a3};
  *(float4*)(part + grp * HW + (yt * 4 + r) * 256 + x0) = res;
}

// ---------------- K5: out_c = (P2c+P2c+1+P8+2c+P9+2c) / (P6+P7+muC) ---------------------
__global__ __launch_bounds__(256) void k_final(const float* __restrict__ part,
                                               const float* __restrict__ mu,
                                               float* __restrict__ out){
  int pix = blockIdx.x * 256 + threadIdx.x;
  float muC = 0.f;
  #pragma unroll
  for (int m = 0; m < 10; ++m){
    float s = 0.f;
    for (int u = 0; u < 65; ++u) s += mu[u * 10 + m];
    muC += s * s;
  }
  float den = part[6 * HW + pix] + part[7 * HW + pix] + muC;
  float inv = 1.f / den;
  #pragma unroll
  for (int c = 0; c < 3; ++c){
    float num = part[(2 * c) * HW + pix] + part[(2 * c + 1) * HW + pix]
              + part[(8 + 2 * c) * HW + pix] + part[(9 + 2 * c) * HW + pix];
    out[c * HW + pix] = num * inv;
  }
}

extern "C" void kernel_launch(void* const* d_in, const int* in_sizes, int n_in,
                              void* d_out, int out_size, void* d_ws, size_t ws_size,
                              hipStream_t stream) {
  const float* img  = (const float*)d_in[0];
  const float* zern = (const float*)d_in[1];
  const float* w1   = (const float*)d_in[2];
  const float* b1   = (const float*)d_in[3];
  const float* w2   = (const float*)d_in[4];
  const float* b2   = (const float*)d_in[5];
  const float* w3   = (const float*)d_in[6];
  const float* b3   = (const float*)d_in[7];
  const float* bl   = (const float*)d_in[8];
  const float* br   = (const float*)d_in[9];
  const float* mu   = (const float*)d_in[10];
  float* out = (float*)d_out;

  float* w     = (float*)d_ws;
  float* tilt  = w;              // planes [0,3)
  float* coefp = w + 3 * HW;     // planes [3,103); dead after vconv10
  float* part  = w + 3 * HW;     // planes [3,17): hconv partials (reuse coefp region)
  float* sbuf  = w + 103 * HW;   // planes [103,143)
  float* smu   = w + 143 * HW;   // planes [143,173)
  unsigned short* wbf = (unsigned short*)sbuf;       // bf16 weights, dead before vconv10
  unsigned short* Tt  = (unsigned short*)(w + 173 * HW); // Toeplitz tables, 61 KB

  k_gridsample<<<256, 256, 0, stream>>>(img, zern, tilt);
  k_wcvt<<<332, 256, 0, stream>>>(w1, w2, w3, wbf);
  k_tz<<<120, 256, 0, stream>>>(bl, mu, Tt);
  k_mlp<<<1024, 256, 0, stream>>>(zern, b1, b2, b3, wbf, coefp);
  k_vconv10<<<688, 256, 0, stream>>>(tilt, coefp, Tt, sbuf, smu);
  k_hconv5<<<896, 256, 0, stream>>>(sbuf, smu, br, mu, part);
  k_final<<<256, 256, 0, stream>>>(part, mu, out);
}

// Round 13
// 170.943 us; speedup vs baseline: 2.6704x; 1.0767x over previous
//
#include <hip/hip_runtime.h>

#define HW 65536

typedef __attribute__((ext_vector_type(8))) short short8;
typedef __attribute__((ext_vector_type(4))) float float4v;

__device__ __forceinline__ int refl(int i){ if (i < 0) i = -i; if (i > 255) i = 510 - i; return i; }
__device__ __forceinline__ float lrelu(float x){ return x > 0.f ? x : 0.01f * x; }
__device__ __forceinline__ unsigned int f2bf(float x){
  union { float f; unsigned int u; } v; v.f = x;
  unsigned int r = v.u + 0x7fff + ((v.u >> 16) & 1);
  return r >> 16;
}

// ---------------- K1: bilinear grid sample (border, align_corners=False) ----------------
__global__ __launch_bounds__(256) void k_gridsample(const float* __restrict__ img,
                                                    const float* __restrict__ zern,
                                                    float* __restrict__ tilt){
  int x = threadIdx.x, y = blockIdx.x;
  int pix = y * 256 + x;
  float px = zern[pix * 35 + 0], py = zern[pix * 35 + 1];
  float ix = ((float)x + px) * (256.f / 255.f) - 0.5f;
  float iy = ((float)y + py) * (256.f / 255.f) - 0.5f;
  ix = fminf(fmaxf(ix, 0.f), 255.f);
  iy = fminf(fmaxf(iy, 0.f), 255.f);
  float x0f = floorf(ix), y0f = floorf(iy);
  float wx = ix - x0f, wy = iy - y0f;
  int x0 = (int)x0f, y0 = (int)y0f;
  int x1 = min(x0 + 1, 255), y1 = min(y0 + 1, 255);
  #pragma unroll
  for (int c = 0; c < 3; ++c){
    const float* im = img + c * HW;
    float g00 = im[y0 * 256 + x0], g01 = im[y0 * 256 + x1];
    float g10 = im[y1 * 256 + x0], g11 = im[y1 * 256 + x1];
    float top = g00 * (1.f - wx) + g01 * wx;
    float bot = g10 * (1.f - wx) + g11 * wx;
    tilt[c * HW + pix] = top * (1.f - wy) + bot * wy;
  }
}

// ---------------- Weight convert: fp32 -> zero-padded bf16 ------------------------------
#define W2OFF 13312
#define W3OFF 59904
__global__ __launch_bounds__(256) void k_wcvt(const float* __restrict__ w1,
    const float* __restrict__ w2, const float* __restrict__ w3,
    unsigned short* __restrict__ wbf){
  int i = blockIdx.x * 256 + threadIdx.x;
  if (i < 208 * 64){
    int n = i >> 6, k = i & 63;
    float v = (n < 200 && k < 33) ? w1[n * 33 + k] : 0.f;
    wbf[i] = (unsigned short)f2bf(v);
  } else if (i < W2OFF + 208 * 224){
    int j = i - W2OFF; int n = j / 224, k = j - n * 224;
    float v = (n < 200 && k < 200) ? w2[n * 200 + k] : 0.f;
    wbf[i] = (unsigned short)f2bf(v);
  } else if (i < 84992){
    int j = i - W3OFF; int n = j / 224, k = j - n * 224;
    float v = (n < 100 && k < 200) ? w3[n * 200 + k] : 0.f;
    wbf[i] = (unsigned short)f2bf(v);
  }
}

// ---------------- Toeplitz tables: 30 x 16 x 96 bf16 = 92 KB ----------------------------
// t<10: bl col t (vconv);  10..19: mu col t-10 (vconv-mu AND hconv-mu);  20..29: br col t-20.
__global__ __launch_bounds__(256) void k_tz(const float* __restrict__ bl,
    const float* __restrict__ br, const float* __restrict__ mu,
    unsigned short* __restrict__ Tt){
  int e = blockIdx.x * 256 + threadIdx.x;
  if (e >= 46080) return;
  int t = e / 1536, rem = e - t * 1536;
  int m = rem / 96, k = rem - m * 96;
  int d = k - m;
  float v = 0.f;
  if (d >= 0 && d <= 64){
    if (t < 10)      v = bl[d * 10 + t];
    else if (t < 20) v = mu[d * 10 + (t - 10)];
    else             v = br[d * 10 + (t - 20)];
  }
  Tt[e] = (unsigned short)f2bf(v);
}

// ---------------- Fused MLP: 32-pixel tile (5 blocks/CU), 3 layers, MFMA bf16 -----------
#define HSTR 232
__global__ __launch_bounds__(256) void k_mlp(const float* __restrict__ zern,
    const float* __restrict__ b1f, const float* __restrict__ b2f,
    const float* __restrict__ b3f, const unsigned short* __restrict__ wbf,
    float* __restrict__ coefp){
  __shared__ char smem[29696];
  unsigned short* H1 = (unsigned short*)smem;                 // 32 x 232 bf16 = 14848 B
  float*          H3 = (float*)smem;                          // 32 x 113 f32  = 14464 B
  unsigned short* XB = (unsigned short*)(smem + 14848);       // 32 x 72 bf16
  unsigned short* H2 = XB;                                    // 32 x 232 bf16
  int tid = threadIdx.x;
  int pix0 = blockIdx.x * 32;
  int lane = tid & 63, wv = tid >> 6;
  int ln = lane & 15, qd = lane >> 4;

  for (int e = tid; e < 1152; e += 256) ((int*)XB)[e] = 0;
  for (int e = tid; e < 384; e += 256){
    int m = e / 12, j = e - m * 12;
    ((int*)H1)[m * 116 + 104 + j] = 0;
  }
  __syncthreads();
  for (int e = tid; e < 32 * 33; e += 256){
    int m = e / 33, k = e - m * 33;
    XB[m * 72 + k] = (unsigned short)f2bf(zern[(pix0 + m) * 35 + 2 + k]);
  }
  __syncthreads();

  // ---- layer 1: X(32x64) x W1^T ----
  for (int nt = wv; nt < 13; nt += 4){
    int n = nt * 16 + ln;
    short8 b0 = *(const short8*)(wbf + n * 64 + qd * 8);
    short8 b1 = *(const short8*)(wbf + n * 64 + 32 + qd * 8);
    float bv = (n < 200) ? b1f[n] : 0.f;
    #pragma unroll
    for (int mt = 0; mt < 2; ++mt){
      float4v acc = {bv, bv, bv, bv};
      short8 a0 = *(const short8*)(XB + (mt * 16 + ln) * 72 + qd * 8);
      short8 a1 = *(const short8*)(XB + (mt * 16 + ln) * 72 + 32 + qd * 8);
      acc = __builtin_amdgcn_mfma_f32_16x16x32_bf16(a0, b0, acc, 0, 0, 0);
      acc = __builtin_amdgcn_mfma_f32_16x16x32_bf16(a1, b1, acc, 0, 0, 0);
      #pragma unroll
      for (int r = 0; r < 4; ++r)
        H1[(mt * 16 + qd * 4 + r) * HSTR + n] = (unsigned short)f2bf(lrelu(acc[r]));
    }
  }
  __syncthreads();

  // ---- layer 2 ----
  for (int e = tid; e < 384; e += 256){
    int m = e / 12, j = e - m * 12;
    ((int*)H2)[m * 116 + 104 + j] = 0;
  }
  {
    const unsigned short* w2p = wbf + W2OFF;
    for (int nt = wv; nt < 13; nt += 4){
      int n = nt * 16 + ln;
      short8 bf[7];
      #pragma unroll
      for (int kc = 0; kc < 7; ++kc)
        bf[kc] = *(const short8*)(w2p + n * 224 + kc * 32 + qd * 8);
      float bv = (n < 200) ? b2f[n] : 0.f;
      #pragma unroll
      for (int mt = 0; mt < 2; ++mt){
        float4v acc = {bv, bv, bv, bv};
        #pragma unroll
        for (int kc = 0; kc < 7; ++kc){
          short8 af = *(const short8*)(H1 + (mt * 16 + ln) * HSTR + kc * 32 + qd * 8);
          acc = __builtin_amdgcn_mfma_f32_16x16x32_bf16(af, bf[kc], acc, 0, 0, 0);
        }
        #pragma unroll
        for (int r = 0; r < 4; ++r)
          H2[(mt * 16 + qd * 4 + r) * HSTR + n] = (unsigned short)f2bf(lrelu(acc[r]));
      }
    }
  }
  __syncthreads();

  // ---- layer 3 ----
  {
    const unsigned short* w3p = wbf + W3OFF;
    for (int nt = wv; nt < 7; nt += 4){
      int n = nt * 16 + ln;
      short8 bf[7];
      #pragma unroll
      for (int kc = 0; kc < 7; ++kc)
        bf[kc] = *(const short8*)(w3p + n * 224 + kc * 32 + qd * 8);
      float bv = (n < 100) ? b3f[n] : 0.f;
      #pragma unroll
      for (int mt = 0; mt < 2; ++mt){
        float4v acc = {bv, bv, bv, bv};
        #pragma unroll
        for (int kc = 0; kc < 7; ++kc){
          short8 af = *(const short8*)(H2 + (mt * 16 + ln) * HSTR + kc * 32 + qd * 8);
          acc = __builtin_amdgcn_mfma_f32_16x16x32_bf16(af, bf[kc], acc, 0, 0, 0);
        }
        #pragma unroll
        for (int r = 0; r < 4; ++r)
          H3[(mt * 16 + qd * 4 + r) * 113 + n] = acc[r];
      }
    }
  }
  __syncthreads();

  for (int e = tid; e < 3200; e += 256){
    int n = e >> 5, m = e & 31;
    coefp[n * HW + pix0 + m] = H3[m * 113 + n];
  }
}

// ---------------- K3 v10: vertical conv as banded-Toeplitz MFMA (unchanged) -------------
#define VB 344
__global__ __launch_bounds__(256) void k_vconv10(const float* __restrict__ tilt,
    const float* __restrict__ coefp, const unsigned short* __restrict__ Tt,
    float* __restrict__ sbuf, float* __restrict__ smu){
  __shared__ __align__(16) unsigned short sxb[16 * VB];
  int tid = threadIdx.x;
  int bid = blockIdx.x;
  int lane = tid & 63, wv = tid >> 6;
  int ln = lane & 15, qd = lane >> 4;
  int col = tid & 15, seg = tid >> 4;
  int r0 = seg * 20;

  int goff[20];
  #pragma unroll
  for (int q = 0; q < 20; ++q) goff[q] = refl(r0 + q - 32) * 256 + col;

  for (int e = tid; e < 384; e += 256){
    int cc = e / 24, rp = e - cc * 24;
    sxb[cc * VB + 320 + rp] = 0;
  }

  if (bid < 640){
    int s = bid & 15;
    int cj = bid >> 4;
    int c = cj / 10, j = cj - c * 10;
    int x0 = s * 16;
    float treg[20];
    if (c < 3){
      const float* tc = tilt + c * HW + x0;
      #pragma unroll
      for (int q = 0; q < 20; ++q) treg[q] = tc[goff[q]];
    }
    float pf[20];
    {
      const float* cq = coefp + j * HW + x0;
      #pragma unroll
      for (int q = 0; q < 20; ++q) pf[q] = cq[goff[q]];
    }
    float4v acc[4];
    #pragma unroll
    for (int t = 0; t < 4; ++t) acc[t] = (float4v){0.f, 0.f, 0.f, 0.f};
    for (int i = 0; i < 10; ++i){
      __syncthreads();
      #pragma unroll
      for (int q = 0; q < 10; ++q){
        float v0 = pf[2 * q], v1 = pf[2 * q + 1];
        if (c < 3){ v0 *= treg[2 * q]; v1 *= treg[2 * q + 1]; }
        unsigned int pk = f2bf(v0) | (f2bf(v1) << 16);
        *(unsigned int*)&sxb[col * VB + r0 + 2 * q] = pk;
      }
      __syncthreads();
      if (i < 9){
        const float* cn = coefp + ((i + 1) * 10 + j) * HW + x0;
        #pragma unroll
        for (int q = 0; q < 20; ++q) pf[q] = cn[goff[q]];
      }
      const unsigned short* ta = Tt + i * 1536 + ln * 96 + qd * 8;
      short8 A0 = *(const short8*)(ta);
      short8 A1 = *(const short8*)(ta + 32);
      short8 A2 = *(const short8*)(ta + 64);
      #pragma unroll
      for (int t = 0; t < 4; ++t){
        int yt = wv * 4 + t;
        const unsigned short* bp = sxb + ln * VB + yt * 16 + qd * 8;
        short8 B0 = *(const short8*)(bp);
        short8 B1 = *(const short8*)(bp + 32);
        short8 B2 = *(const short8*)(bp + 64);
        acc[t] = __builtin_amdgcn_mfma_f32_16x16x32_bf16(A0, B0, acc[t], 0, 0, 0);
        acc[t] = __builtin_amdgcn_mfma_f32_16x16x32_bf16(A1, B1, acc[t], 0, 0, 0);
        acc[t] = __builtin_amdgcn_mfma_f32_16x16x32_bf16(A2, B2, acc[t], 0, 0, 0);
      }
    }
    float* S = sbuf + (c * 10 + j) * HW + x0 + ln;
    #pragma unroll
    for (int t = 0; t < 4; ++t){
      int yt = wv * 4 + t;
      #pragma unroll
      for (int r = 0; r < 4; ++r)
        S[(yt * 16 + qd * 4 + r) * 256] = acc[t][r];
    }
  } else {
    int b2 = bid - 640;
    int c = b2 >> 4, s = b2 & 15;
    int x0 = s * 16;
    const float* tc = tilt + c * HW + x0;
    float tv[20];
    #pragma unroll
    for (int q = 0; q < 20; ++q) tv[q] = tc[goff[q]];
    #pragma unroll
    for (int q = 0; q < 10; ++q){
      unsigned int pk = f2bf(tv[2 * q]) | (f2bf(tv[2 * q + 1]) << 16);
      *(unsigned int*)&sxb[col * VB + r0 + 2 * q] = pk;
    }
    __syncthreads();
    for (int m = 0; m < 10; ++m){
      const unsigned short* ta = Tt + (10 + m) * 1536 + ln * 96 + qd * 8;
      short8 A0 = *(const short8*)(ta);
      short8 A1 = *(const short8*)(ta + 32);
      short8 A2 = *(const short8*)(ta + 64);
      float4v acc[4];
      #pragma unroll
      for (int t = 0; t < 4; ++t) acc[t] = (float4v){0.f, 0.f, 0.f, 0.f};
      #pragma unroll
      for (int t = 0; t < 4; ++t){
        int yt = wv * 4 + t;
        const unsigned short* bp = sxb + ln * VB + yt * 16 + qd * 8;
        short8 B0 = *(const short8*)(bp);
        short8 B1 = *(const short8*)(bp + 32);
        short8 B2 = *(const short8*)(bp + 64);
        acc[t] = __builtin_amdgcn_mfma_f32_16x16x32_bf16(A0, B0, acc[t], 0, 0, 0);
        acc[t] = __builtin_amdgcn_mfma_f32_16x16x32_bf16(A1, B1, acc[t], 0, 0, 0);
        acc[t] = __builtin_amdgcn_mfma_f32_16x16x32_bf16(A2, B2, acc[t], 0, 0, 0);
      }
      float* S = smu + (c * 10 + m) * HW + x0 + ln;
      #pragma unroll
      for (int t = 0; t < 4; ++t){
        int yt = wv * 4 + t;
        #pragma unroll
        for (int r = 0; r < 4; ++r)
          S[(yt * 16 + qd * 4 + r) * 256] = acc[t][r];
      }
    }
  }
}

// ---------------- K4 v8: horizontal conv as banded-Toeplitz MFMA ------------------------
// 224 blocks = 14 groups x 16 y-tiles. D[m=x_out 16][n=y 16] = A(R/mu Toeplitz) . B(S rows).
// B staged as bf16 [16 rows y][320 cols x(-32..287)], row stride 328 shorts (B-reads 2-way).
#define HS2 328
__global__ __launch_bounds__(256) void k_hconv8(const float* __restrict__ sbuf,
    const float* __restrict__ smu, const unsigned short* __restrict__ Tt,
    float* __restrict__ part){
  __shared__ __align__(16) unsigned short sxb[16 * HS2];
  int tid = threadIdx.x;
  int grp = blockIdx.x >> 4;
  int yt  = blockIdx.x & 15;
  int y0 = yt * 16;
  int lane = tid & 63, wv = tid >> 6;
  int ln = lane & 15, qd = lane >> 4;
  int srow = tid >> 4, scol = tid & 15;
  int isbr = (grp < 8);
  int tgt, h;
  if (isbr){ tgt = grp >> 1; h = grp & 1; }
  else     { int g2 = grp - 8; tgt = g2 >> 1; h = g2 & 1; }
  const float* base = isbr ? (sbuf + tgt * 10 * HW) : (smu + tgt * 10 * HW);
  int tbase = isbr ? 20 : 10;

  int gx[20];
  #pragma unroll
  for (int q = 0; q < 20; ++q) gx[q] = refl(scol * 20 - 32 + q);

  float4v acc[4];
  #pragma unroll
  for (int t = 0; t < 4; ++t) acc[t] = (float4v){0.f, 0.f, 0.f, 0.f};

  for (int p = 0; p < 5; ++p){
    int col = h * 5 + p;
    const float* plane = base + col * HW + (y0 + srow) * 256;
    __syncthreads();
    float v[20];
    #pragma unroll
    for (int q = 0; q < 20; ++q) v[q] = plane[gx[q]];
    #pragma unroll
    for (int q = 0; q < 10; ++q){
      unsigned int pk = f2bf(v[2 * q]) | (f2bf(v[2 * q + 1]) << 16);
      *(unsigned int*)&sxb[srow * HS2 + scol * 20 + 2 * q] = pk;
    }
    __syncthreads();
    const unsigned short* ta = Tt + (tbase + col) * 1536 + ln * 96 + qd * 8;
    short8 A0 = *(const short8*)(ta);
    short8 A1 = *(const short8*)(ta + 32);
    short8 A2 = *(const short8*)(ta + 64);
    #pragma unroll
    for (int t = 0; t < 4; ++t){
      int wt = wv * 4 + t;
      const unsigned short* bp = sxb + ln * HS2 + wt * 16 + qd * 8;
      short8 B0 = *(const short8*)(bp);
      short8 B1 = *(const short8*)(bp + 32);
      short8 B2 = *(const short8*)(bp + 64);
      acc[t] = __builtin_amdgcn_mfma_f32_16x16x32_bf16(A0, B0, acc[t], 0, 0, 0);
      acc[t] = __builtin_amdgcn_mfma_f32_16x16x32_bf16(A1, B1, acc[t], 0, 0, 0);
      acc[t] = __builtin_amdgcn_mfma_f32_16x16x32_bf16(A2, B2, acc[t], 0, 0, 0);
    }
  }
  #pragma unroll
  for (int t = 0; t < 4; ++t){
    int wt = wv * 4 + t;
    float4 res = {acc[t][0], acc[t][1], acc[t][2], acc[t][3]};
    *(float4*)(part + grp * HW + (y0 + ln) * 256 + wt * 16 + qd * 4) = res;
  }
}

// ---------------- K5: out_c = (P2c+P2c+1+P8+2c+P9+2c) / (P6+P7+muC) ---------------------
__global__ __launch_bounds__(256) void k_final(const float* __restrict__ part,
                                               const float* __restrict__ mu,
                                               float* __restrict__ out){
  int pix = blockIdx.x * 256 + threadIdx.x;
  float muC = 0.f;
  #pragma unroll
  for (int m = 0; m < 10; ++m){
    float s = 0.f;
    for (int u = 0; u < 65; ++u) s += mu[u * 10 + m];
    muC += s * s;
  }
  float den = part[6 * HW + pix] + part[7 * HW + pix] + muC;
  float inv = 1.f / den;
  #pragma unroll
  for (int c = 0; c < 3; ++c){
    float num = part[(2 * c) * HW + pix] + part[(2 * c + 1) * HW + pix]
              + part[(8 + 2 * c) * HW + pix] + part[(9 + 2 * c) * HW + pix];
    out[c * HW + pix] = num * inv;
  }
}

extern "C" void kernel_launch(void* const* d_in, const int* in_sizes, int n_in,
                              void* d_out, int out_size, void* d_ws, size_t ws_size,
                              hipStream_t stream) {
  const float* img  = (const float*)d_in[0];
  const float* zern = (const float*)d_in[1];
  const float* w1   = (const float*)d_in[2];
  const float* b1   = (const float*)d_in[3];
  const float* w2   = (const float*)d_in[4];
  const float* b2   = (const float*)d_in[5];
  const float* w3   = (const float*)d_in[6];
  const float* b3   = (const float*)d_in[7];
  const float* bl   = (const float*)d_in[8];
  const float* br   = (const float*)d_in[9];
  const float* mu   = (const float*)d_in[10];
  float* out = (float*)d_out;

  float* w     = (float*)d_ws;
  float* tilt  = w;              // planes [0,3)
  float* coefp = w + 3 * HW;     // planes [3,103); dead after vconv10
  float* part  = w + 3 * HW;     // planes [3,17): hconv partials (reuse coefp region)
  float* sbuf  = w + 103 * HW;   // planes [103,143)
  float* smu   = w + 143 * HW;   // planes [143,173)
  unsigned short* wbf = (unsigned short*)sbuf;           // bf16 weights, dead before vconv10
  unsigned short* Tt  = (unsigned short*)(w + 173 * HW); // Toeplitz tables, 92 KB

  k_gridsample<<<256, 256, 0, stream>>>(img, zern, tilt);
  k_wcvt<<<332, 256, 0, stream>>>(w1, w2, w3, wbf);
  k_tz<<<180, 256, 0, stream>>>(bl, br, mu, Tt);
  k_mlp<<<2048, 256, 0, stream>>>(zern, b1, b2, b3, wbf, coefp);
  k_vconv10<<<688, 256, 0, stream>>>(tilt, coefp, Tt, sbuf, smu);
  k_hconv8<<<224, 256, 0, stream>>>(sbuf, smu, Tt, part);
  k_final<<<256, 256, 0, stream>>>(part, mu, out);
}